// Round 5
// baseline (2486.737 us; speedup 1.0000x reference)
//
#include <hip/hip_runtime.h>
#include <hip/hip_bf16.h>

#define DD 1024
#define MDD 256
#define LL 2048
#define BB 4
#define NROWS (BB*LL)   // 8192

typedef short bf16x8 __attribute__((ext_vector_type(8)));
typedef float f32x4 __attribute__((ext_vector_type(4)));
typedef int   i32x4 __attribute__((ext_vector_type(4)));

__device__ __forceinline__ short f2b(float x){
  __hip_bfloat16 h = __float2bfloat16(x);
  return *reinterpret_cast<short*>(&h);
}
__device__ __forceinline__ float b2f(short s){
  return __uint_as_float(((unsigned)(unsigned short)s) << 16);
}
__device__ __forceinline__ float frcp(float x){
#if __has_builtin(__builtin_amdgcn_rcpf)
  return __builtin_amdgcn_rcpf(x);
#else
  float r; asm("v_rcp_f32 %0, %1" : "=v"(r) : "v"(x)); return r;
#endif
}
__device__ __forceinline__ float fsigmoid(float x){
  return frcp(1.f + __expf(-x));
}
// select a[kg] without dynamic vector indexing (rule #20): 3 cndmask
__device__ __forceinline__ float sel4(f32x4 a, int kg){
  float lo = (kg & 1) ? a[1] : a[0];
  float hi = (kg & 1) ? a[3] : a[2];
  return (kg & 2) ? hi : lo;
}

// ---------------- fused weight conversion / bias prep (one launch) ----------------
struct CvtDesc {
  const float* src; const float* src2; short* dstb; float* dstf;
  int n, cols, sld, soff, dld, mode;
};
struct CvtArgs { CvtDesc d[20]; };

__global__ __launch_bounds__(256) void cvt_all(CvtArgs a){
  int di = blockIdx.x >> 6;
  CvtDesc d = a.d[di];
  int base = (blockIdx.x & 63)*256 + threadIdx.x;
  for (int i = base; i < d.n; i += 64*256){
    int r = i / d.cols, c = i - r*d.cols;
    float v = d.src[(size_t)r*d.sld + d.soff + c];
    if (d.mode == 2) v += d.src2[i];
    if (d.mode == 0) d.dstb[(size_t)r*d.dld + c] = f2b(v);
    else             d.dstf[i] = v;
  }
}

// ---------------- rmsnorm (f32 in -> bf16 out, strided out) ----------------
__global__ __launch_bounds__(256) void rmsnorm_k(const float* __restrict__ x,
                                                 const float* __restrict__ w,
                                                 short* __restrict__ xn){
  int row = blockIdx.x, tid = threadIdx.x;
  const float* xr = x + (size_t)row*DD;
  float4 v = *(const float4*)&xr[tid*4];
  float ss = v.x*v.x + v.y*v.y + v.z*v.z + v.w*v.w;
  __shared__ float red[256];
  red[tid] = ss; __syncthreads();
  for (int s = 128; s > 0; s >>= 1){ if (tid < s) red[tid] += red[tid+s]; __syncthreads(); }
  float scale = rsqrtf(red[0]/(float)DD + 1e-6f);
  const float* wr = w + tid*4;
  short4 o;
  o.x = f2b(v.x*wr[0]*scale); o.y = f2b(v.y*wr[1]*scale);
  o.z = f2b(v.z*wr[2]*scale); o.w = f2b(v.w*wr[3]*scale);
  *(short4*)&xn[(size_t)row*2048 + tid*4] = o;
}

// ---------------- depthwise causal conv K=5 (strided in/out: A2 layout) ----------------
__global__ __launch_bounds__(256) void dwconv_k(const short* __restrict__ xnA,
                                                const float* __restrict__ dwk,
                                                const float* __restrict__ dwb,
                                                short* __restrict__ xcA){
  size_t i = (size_t)blockIdx.x*256 + threadIdx.x;  // over NROWS*DD
  int d = (int)(i & (DD-1));
  int l = (int)((i >> 10) & (LL-1));
  int b = (int)(i >> 21);
  float acc = dwb[d];
  const float* kk = dwk + d*5;
  #pragma unroll
  for (int k = 0; k < 5; ++k){
    int ll = l + k - 4;
    if (ll >= 0) acc += b2f(xnA[((size_t)(b*LL + ll))*2048 + d]) * kk[k];
  }
  xcA[((size_t)(b*LL + l))*2048 + 1024 + d] = f2b(acc);
}

// ---------------- generic bf16 MFMA GEMM: C = act(A @ Bw^T + bias) (+adds) ----------------
// OUTMODE: 0=f32 store, 1=f32 accumulate, 2=bf16 store, 3=f32 accumulate + bf16 2nd out.
// ACT: 0 none, 1 silu, 2 exact gelu. DUAL: blocks >= nsplit use the _b pointer set.
template<int ACT, int OUTMODE, int PERMUTE, int DUAL>
__global__ __launch_bounds__(256) void gemm_bt(
    const short* __restrict__ A, const short* __restrict__ Bw,
    const float* __restrict__ bias, const float* __restrict__ add0,
    const float* __restrict__ add1, void* __restrict__ Cout, short* __restrict__ Cout2,
    const short* A_b, const short* Bw_b, const float* bias_b, void* Cout_b,
    int M, int N, int K, int lda, int ldb, int nbn, int nsplit){
  __shared__ __align__(16) short As[128*32];
  __shared__ __align__(16) short Bs[128*32];
  int bid = blockIdx.x;
  if (DUAL && bid >= nsplit){
    A = A_b; Bw = Bw_b; bias = bias_b; Cout = Cout_b; bid -= nsplit;
  }
  int bm = bid / nbn, bn = bid % nbn;
  int tid = threadIdx.x, lane = tid & 63, w = tid >> 6;
  int wm = (w >> 1)*64, wn = (w & 1)*64;
  const int r0 = lane & 15, kg = lane >> 4;

  f32x4 acc[4][4];
  #pragma unroll
  for (int i = 0; i < 4; ++i)
    #pragma unroll
    for (int j = 0; j < 4; ++j)
      #pragma unroll
      for (int r = 0; r < 4; ++r) acc[i][j][r] = 0.f;

  const int c0 = w*64 + lane;
  const int c1 = c0 + 256;
  const short* a0 = &A [(size_t)(bm*128 + (c0 >> 2))*lda + (c0 & 3)*8];
  const short* a1 = &A [(size_t)(bm*128 + (c1 >> 2))*lda + (c1 & 3)*8];
  const short* b0 = &Bw[(size_t)(bn*128 + (c0 >> 2))*ldb + (c0 & 3)*8];
  const short* b1 = &Bw[(size_t)(bn*128 + (c1 >> 2))*ldb + (c1 & 3)*8];

  for (int k0 = 0; k0 < K; k0 += 32){
    __builtin_amdgcn_global_load_lds((const __attribute__((address_space(1))) void*)(a0 + k0),
                                     (__attribute__((address_space(3))) void*)&As[w*512], 16, 0, 0);
    __builtin_amdgcn_global_load_lds((const __attribute__((address_space(1))) void*)(b0 + k0),
                                     (__attribute__((address_space(3))) void*)&Bs[w*512], 16, 0, 0);
    __builtin_amdgcn_global_load_lds((const __attribute__((address_space(1))) void*)(a1 + k0),
                                     (__attribute__((address_space(3))) void*)&As[2048 + w*512], 16, 0, 0);
    __builtin_amdgcn_global_load_lds((const __attribute__((address_space(1))) void*)(b1 + k0),
                                     (__attribute__((address_space(3))) void*)&Bs[2048 + w*512], 16, 0, 0);
    __syncthreads();
    bf16x8 av[4], bv[4];
    #pragma unroll
    for (int i = 0; i < 4; ++i) av[i] = *(const bf16x8*)&As[(wm + i*16 + r0)*32 + kg*8];
    #pragma unroll
    for (int j = 0; j < 4; ++j) bv[j] = *(const bf16x8*)&Bs[(wn + j*16 + r0)*32 + kg*8];
    #pragma unroll
    for (int i = 0; i < 4; ++i)
      #pragma unroll
      for (int j = 0; j < 4; ++j)
        acc[i][j] = __builtin_amdgcn_mfma_f32_16x16x32_bf16(av[i], bv[j], acc[i][j], 0, 0, 0);
    __syncthreads();
  }

  #pragma unroll
  for (int i = 0; i < 4; ++i){
    int grb = bm*128 + wm + i*16 + kg*4;
    #pragma unroll
    for (int j = 0; j < 4; ++j){
      int gc = bn*128 + wn + j*16 + r0;
      float bvv = bias ? bias[gc] : 0.f;
      #pragma unroll
      for (int r = 0; r < 4; ++r){
        int gr = grb + r;
        float v = acc[i][j][r] + bvv;
        if (ACT == 1) v = v / (1.f + __expf(-v));
        else if (ACT == 2) v = 0.5f*v*(1.f + erff(v*0.70710678118f));
        size_t orow = PERMUTE ? (size_t)((gr & 3)*LL + (gr >> 2)) : (size_t)gr;
        size_t oi = orow*(size_t)N + gc;
        if (add0) v += add0[oi];
        if (add1) v += add1[oi];
        if (OUTMODE == 0) ((float*)Cout)[oi] = v;
        else if (OUTMODE == 1) ((float*)Cout)[oi] += v;
        else if (OUTMODE == 2) ((short*)Cout)[oi] = f2b(v);
        else {
          float nv = ((float*)Cout)[oi] + v;
          ((float*)Cout)[oi] = nv;
          Cout2[oi] = f2b(nv);
        }
      }
    }
  }
}

// ---------------- fused: block 0 = sequential scan; blocks 1.. = G34 GEMM ----------------
__global__ __launch_bounds__(512, 2) void scan_g34_k(
    const float* __restrict__ fxu, const short* __restrict__ Wfu,
    const float* __restrict__ m0, short* __restrict__ m2all, float* __restrict__ newmem,
    const short* __restrict__ A2, const short* __restrict__ B2,
    const float* __restrict__ bias2, const float* __restrict__ xres,
    float* __restrict__ ybuf){
  __shared__ __align__(16) short lds[8192];   // 16KB; scan uses first 2176 shorts
  const int tid = threadIdx.x, lane = tid & 63, w = tid >> 6;
  const int r0 = lane & 15, kg = lane >> 4;

  if (blockIdx.x != 0){
    // ---------- G34 GEMM branch: 128x128 tile, 8 waves (wave = 64x32 subtile) ----------
    int bid = (int)blockIdx.x - 1;
    int bm = bid >> 3, bn = bid & 7;
    short* As = lds;          // [128][32]
    short* Bs = lds + 4096;
    int wm = (w >> 2)*64, wn = (w & 3)*32;
    f32x4 acc[4][2];
    #pragma unroll
    for (int i = 0; i < 4; ++i)
      #pragma unroll
      for (int j = 0; j < 2; ++j)
        #pragma unroll
        for (int r = 0; r < 4; ++r) acc[i][j][r] = 0.f;

    const int c = tid;  // chunk 0..511: row=c>>2, seg=c&3
    const short* ag = &A2[(size_t)(bm*128 + (c >> 2))*2048 + (c & 3)*8];
    const short* bg = &B2[(size_t)(bn*128 + (c >> 2))*2048 + (c & 3)*8];

    for (int k0 = 0; k0 < 2048; k0 += 32){
      __builtin_amdgcn_global_load_lds((const __attribute__((address_space(1))) void*)(ag + k0),
                                       (__attribute__((address_space(3))) void*)&As[w*512], 16, 0, 0);
      __builtin_amdgcn_global_load_lds((const __attribute__((address_space(1))) void*)(bg + k0),
                                       (__attribute__((address_space(3))) void*)&Bs[w*512], 16, 0, 0);
      __syncthreads();
      bf16x8 av[4], bv[2];
      #pragma unroll
      for (int i = 0; i < 4; ++i) av[i] = *(const bf16x8*)&As[(wm + i*16 + r0)*32 + kg*8];
      #pragma unroll
      for (int j = 0; j < 2; ++j) bv[j] = *(const bf16x8*)&Bs[(wn + j*16 + r0)*32 + kg*8];
      #pragma unroll
      for (int i = 0; i < 4; ++i)
        #pragma unroll
        for (int j = 0; j < 2; ++j)
          acc[i][j] = __builtin_amdgcn_mfma_f32_16x16x32_bf16(av[i], bv[j], acc[i][j], 0, 0, 0);
      __syncthreads();
    }
    #pragma unroll
    for (int i = 0; i < 4; ++i){
      int grb = bm*128 + wm + i*16 + kg*4;
      #pragma unroll
      for (int j = 0; j < 2; ++j){
        int gc = bn*128 + wn + j*16 + r0;
        float bvv = bias2[gc];
        #pragma unroll
        for (int r = 0; r < 4; ++r){
          size_t oi = (size_t)(grb + r)*1024 + gc;
          ybuf[oi] = acc[i][j][r] + bvv + xres[oi];
        }
      }
    }
    return;
  }

  // ---------- scan branch (block 0) ----------
  short* mA0 = lds;            // [4][272] x2 buffers
  short* mA1 = lds + 1088;
  const int j0 = w*32 + r0;

  // gate weights resident in VGPRs (128 VGPR): laundered through opaque asm so the
  // compiler cannot rematerialize the global loads inside the 2048-step loop.
  bf16x8 bw[2][2][8];
  #pragma unroll
  for (int fu = 0; fu < 2; ++fu)
    #pragma unroll
    for (int p = 0; p < 2; ++p)
      #pragma unroll
      for (int kt = 0; kt < 8; ++kt){
        bw[fu][p][kt] = *(const bf16x8*)&Wfu[(size_t)(fu*256 + w*32 + p*16 + r0)*256 + kt*32 + kg*8];
        i32x4* pi = (i32x4*)&bw[fu][p][kt];
        asm volatile("" : "+v"(*pi));
      }

  float m_reg0 = m0[kg*256 + j0];
  float m_reg1 = m0[kg*256 + j0 + 16];

  // step-t f/u raw (ready), step-t xm (ready), step-(t+1) x raw (in flight)
  float cf0, cf1, cu0, cu1, xmc0, xmc1, nx0, nx1;
  {
    size_t b0 = (size_t)kg*LL*768;
    cf0 = fxu[b0 + j0];        cf1 = fxu[b0 + j0 + 16];
    cu0 = fxu[b0 + 256 + j0];  cu1 = fxu[b0 + 256 + j0 + 16];
    float tx0 = fxu[b0 + 512 + j0], tx1 = fxu[b0 + 512 + j0 + 16];
    xmc0 = tx0*fsigmoid(tx0);  xmc1 = tx1*fsigmoid(tx1);
    size_t b1 = b0 + 768;
    nx0 = fxu[b1 + 512 + j0];  nx1 = fxu[b1 + 512 + j0 + 16];
  }
  mA0[kg*272 + j0]      = f2b(m_reg0);
  mA0[kg*272 + j0 + 16] = f2b(m_reg1);
  __syncthreads();

  // prologue: issue A-fragment reads for t=0
  bf16x8 af[8];
  #pragma unroll
  for (int kt = 0; kt < 8; ++kt)
    af[kt] = *(const bf16x8*)&mA0[(r0 & 3)*272 + kt*32 + kg*8];

  for (int t = 0; t < LL; ++t){
    short* man = (t & 1) ? mA0 : mA1;

    // next-step xm: depends only on nx (issued >=1 full step ago) -> overlaps MFMA phase
    float xmn0 = nx0*fsigmoid(nx0);
    float xmn1 = nx1*fsigmoid(nx1);

    __builtin_amdgcn_s_setprio(1);
    f32x4 aF0 = {0.f,0.f,0.f,0.f}, aF1 = {0.f,0.f,0.f,0.f};
    f32x4 aU0 = {0.f,0.f,0.f,0.f}, aU1 = {0.f,0.f,0.f,0.f};
    #pragma unroll
    for (int kt = 0; kt < 8; ++kt){
      aF0 = __builtin_amdgcn_mfma_f32_16x16x32_bf16(af[kt], bw[0][0][kt], aF0, 0, 0, 0);
      aF1 = __builtin_amdgcn_mfma_f32_16x16x32_bf16(af[kt], bw[0][1][kt], aF1, 0, 0, 0);
      aU0 = __builtin_amdgcn_mfma_f32_16x16x32_bf16(af[kt], bw[1][0][kt], aU0, 0, 0, 0);
      aU1 = __builtin_amdgcn_mfma_f32_16x16x32_bf16(af[kt], bw[1][1][kt], aU1, 0, 0, 0);
    }
    __builtin_amdgcn_s_setprio(0);

    float gF0 = sel4(aF0, kg), gF1 = sel4(aF1, kg);
    float gU0 = sel4(aU0, kg), gU1 = sel4(aU1, kg);

    float f0 = fsigmoid(gF0 + cf0);
    float f1 = fsigmoid(gF1 + cf1);
    float u0 = fsigmoid(gU0 + cu0);
    float u1 = fsigmoid(gU1 + cu1);
    m_reg0 = f0*m_reg0 + u0*xmc0;
    m_reg1 = f1*m_reg1 + u1*xmc1;
    short mb0 = f2b(m_reg0), mb1 = f2b(m_reg1);

    // publish m_t into the other buffer; only LDS must drain before barrier
    man[kg*272 + j0]      = mb0;
    man[kg*272 + j0 + 16] = mb1;
    asm volatile("s_waitcnt lgkmcnt(0)" ::: "memory");
    __builtin_amdgcn_sched_barrier(0);
    __builtin_amdgcn_s_barrier();
    __builtin_amdgcn_sched_barrier(0);

    // post-barrier: issue next step's A-fragment reads FIRST (critical path) ...
    if (t + 1 < LL){
      #pragma unroll
      for (int kt = 0; kt < 8; ++kt)
        af[kt] = *(const bf16x8*)&man[(r0 & 3)*272 + kt*32 + kg*8];
    }
    __builtin_amdgcn_sched_barrier(0);

    // ... then hide the global stores + prefetch issue under the ds_read latency
    m2all[(size_t)(t*4 + kg)*256 + j0]      = mb0;
    m2all[(size_t)(t*4 + kg)*256 + j0 + 16] = mb1;

    xmc0 = xmn0; xmc1 = xmn1;
    int t1 = (t + 1 < LL) ? t + 1 : t;
    int t2 = (t + 2 < LL) ? t + 2 : t;
    size_t bfu = ((size_t)kg*LL + t1)*768;
    size_t bx  = ((size_t)kg*LL + t2)*768;
    cf0 = fxu[bfu + j0];        cf1 = fxu[bfu + j0 + 16];
    cu0 = fxu[bfu + 256 + j0];  cu1 = fxu[bfu + 256 + j0 + 16];
    nx0 = fxu[bx + 512 + j0];   nx1 = fxu[bx + 512 + j0 + 16];
  }

  newmem[kg*256 + j0]      = m_reg0;
  newmem[kg*256 + j0 + 16] = m_reg1;
}

// ---------------- router + expert combine + final rmsnorm ----------------
__global__ __launch_bounds__(256) void combine_k(
    float* __restrict__ y, const short* __restrict__ e0, const short* __restrict__ e1,
    const float* __restrict__ rw, const float* __restrict__ rb,
    const float* __restrict__ fw, short* __restrict__ y2bf){
  int row = blockIdx.x, tid = threadIdx.x;
  size_t base = (size_t)row*DD + tid*4;
  float4 vy = *(const float4*)&y[base];
  short4 s0 = *(const short4*)&e0[base];
  short4 s1 = *(const short4*)&e1[base];
  float4 w0 = *(const float4*)&rw[tid*4];
  float4 w1 = *(const float4*)&rw[DD + tid*4];
  float d0 = vy.x*w0.x + vy.y*w0.y + vy.z*w0.z + vy.w*w0.w;
  float d1 = vy.x*w1.x + vy.y*w1.y + vy.z*w1.z + vy.w*w1.w;
  __shared__ float redA[256], redB[256];
  redA[tid] = d0; redB[tid] = d1; __syncthreads();
  for (int s = 128; s > 0; s >>= 1){
    if (tid < s){ redA[tid] += redA[tid+s]; redB[tid] += redB[tid+s]; }
    __syncthreads();
  }
  float l0 = redA[0] + rb[0], l1 = redB[0] + rb[1];
  float p0 = 1.f/(1.f + __expf(l1 - l0));
  float p1 = 1.f - p0;
  float c0 = vy.x + p0*b2f(s0.x) + p1*b2f(s1.x);
  float c1 = vy.y + p0*b2f(s0.y) + p1*b2f(s1.y);
  float c2 = vy.z + p0*b2f(s0.z) + p1*b2f(s1.z);
  float c3 = vy.w + p0*b2f(s0.w) + p1*b2f(s1.w);
  float ss = c0*c0 + c1*c1 + c2*c2 + c3*c3;
  __syncthreads();
  redA[tid] = ss; __syncthreads();
  for (int s = 128; s > 0; s >>= 1){
    if (tid < s) redA[tid] += redA[tid+s];
    __syncthreads();
  }
  float scale = rsqrtf(redA[0]/(float)DD + 1e-6f);
  const float* fwp = fw + tid*4;
  float o0 = c0*fwp[0]*scale, o1 = c1*fwp[1]*scale, o2 = c2*fwp[2]*scale, o3 = c3*fwp[3]*scale;
  float4 ov; ov.x = o0; ov.y = o1; ov.z = o2; ov.w = o3;
  *(float4*)&y[base] = ov;
  short4 ob; ob.x = f2b(o0); ob.y = f2b(o1); ob.z = f2b(o2); ob.w = f2b(o3);
  *(short4*)&y2bf[base] = ob;
}

// ---------------- host ----------------
extern "C" void kernel_launch(void* const* d_in, const int* in_sizes, int n_in,
                              void* d_out, int out_size, void* d_ws, size_t ws_size,
                              hipStream_t stream){
  (void)in_sizes; (void)n_in; (void)out_size; (void)ws_size;
  const float* x     = (const float*)d_in[0];
  const float* mem0  = (const float*)d_in[1];
  const float* normw = (const float*)d_in[2];
  const float* dwk   = (const float*)d_in[3];
  const float* dwb   = (const float*)d_in[4];
  const float* pw    = (const float*)d_in[5];
  const float* pwb   = (const float*)d_in[6];
  const float* Win_w = (const float*)d_in[7];
  const float* Win_b = (const float*)d_in[8];
  const float* Wf_w  = (const float*)d_in[9];
  const float* Wf_b  = (const float*)d_in[10];
  const float* Wu_w  = (const float*)d_in[11];
  const float* Wu_b  = (const float*)d_in[12];
  const float* Wo_w  = (const float*)d_in[13];
  const float* Wo_b  = (const float*)d_in[14];
  const float* rw    = (const float*)d_in[15];
  const float* rb    = (const float*)d_in[16];
  const float* e0w1  = (const float*)d_in[17];
  const float* e0b1  = (const float*)d_in[18];
  const float* e0w2  = (const float*)d_in[19];
  const float* e0b2  = (const float*)d_in[20];
  const float* e1w1  = (const float*)d_in[21];
  const float* e1b1  = (const float*)d_in[22];
  const float* e1w2  = (const float*)d_in[23];
  const float* e1b2  = (const float*)d_in[24];
  const float* fnw   = (const float*)d_in[25];
  const float* dnw   = (const float*)d_in[26];
  const float* dnb   = (const float*)d_in[27];
  const float* upw   = (const float*)d_in[28];
  const float* upb   = (const float*)d_in[29];

  char* ws = (char*)d_ws;
  size_t off = 0;
  auto alloc = [&](size_t bytes)->char*{
    char* p = ws + off; off += (bytes + 255) & ~(size_t)255; return p;
  };
  short* A2       = (short*)alloc((size_t)NROWS*2048*2);   // [xn | xc] bf16
  short* B2       = (short*)alloc((size_t)1024*2048*2);    // [Wo_x | pw] bf16
  short* W_fxuwin = (short*)alloc((size_t)768*1024*2);
  short* W_fum    = (short*)alloc((size_t)512*256*2);
  short* W_om     = (short*)alloc((size_t)1024*256*2);
  short* W_e01    = (short*)alloc((size_t)2048*1024*2);    // [e0w1 ; e1w1]
  short* W_e0w2   = (short*)alloc((size_t)1024*1024*2);
  short* W_e1w2   = (short*)alloc((size_t)1024*1024*2);
  short* W_down   = (short*)alloc((size_t)256*1024*2);
  short* W_up     = (short*)alloc((size_t)1024*256*2);
  float* bias768  = (float*)alloc(768*4);
  float* bias2    = (float*)alloc(1024*4);
  float* bias01   = (float*)alloc(2048*4);
  float* fxu      = (float*)alloc((size_t)NROWS*768*4);
  float* ybuf     = (float*)alloc((size_t)NROWS*DD*4);
  short* m2all    = (short*)alloc((size_t)NROWS*MDD*2);
  short* ybf      = (short*)alloc((size_t)NROWS*DD*2);
  short* e0v      = (short*)alloc((size_t)NROWS*DD*2);
  short* e1v      = (short*)alloc((size_t)NROWS*DD*2);
  short* h01      = (short*)alloc((size_t)NROWS*2048*2);   // [h0 | h1]
  short* hd = m2all;   // m2all dead after G5
  short* y2bf = ybf;   // ybf dead after expert first GEMM
  float* y2   = ybuf;  // in-place rmsnorm

  // ---- one fused weight-conversion launch (20 descriptors x 64 blocks) ----
  CvtArgs ca;
  auto D0 = [&](const float* s, short* db, int rows, int cols, int sld, int soff, int dld){
    return CvtDesc{s, nullptr, db, nullptr, rows*cols, cols, sld, soff, dld, 0};
  };
  auto D1 = [&](const float* s, float* df, int n){
    return CvtDesc{s, nullptr, nullptr, df, n, n, 0, 0, 0, 1};
  };
  ca.d[0]  = D0(Wo_w,  B2,                1024, 1024, 1280, 0,    2048);
  ca.d[1]  = D0(pw,    B2+1024,           1024, 1024, 1024, 0,    2048);
  ca.d[2]  = D0(Wf_w,  W_fxuwin,           256, 1024, 1280, 0,    1024);
  ca.d[3]  = D0(Wu_w,  W_fxuwin+256*1024,  256, 1024, 1280, 0,    1024);
  ca.d[4]  = D0(Win_w, W_fxuwin+512*1024,  256, 1024, 1024, 0,    1024);
  ca.d[5]  = D0(Wf_w,  W_fum,              256,  256, 1280, 1024, 256);
  ca.d[6]  = D0(Wu_w,  W_fum+256*256,      256,  256, 1280, 1024, 256);
  ca.d[7]  = D0(Wo_w,  W_om,              1024,  256, 1280, 1024, 256);
  ca.d[8]  = D0(e0w1,  W_e01,             1024, 1024, 1024, 0,    1024);
  ca.d[9]  = D0(e1w1,  W_e01+1024*1024,   1024, 1024, 1024, 0,    1024);
  ca.d[10] = D0(e0w2,  W_e0w2,            1024, 1024, 1024, 0,    1024);
  ca.d[11] = D0(e1w2,  W_e1w2,            1024, 1024, 1024, 0,    1024);
  ca.d[12] = D0(dnw,   W_down,             256, 1024, 1024, 0,    1024);
  ca.d[13] = D0(upw,   W_up,              1024,  256,  256, 0,    256);
  ca.d[14] = D1(Wf_b,  bias768,       256);
  ca.d[15] = D1(Wu_b,  bias768+256,   256);
  ca.d[16] = D1(Win_b, bias768+512,   256);
  ca.d[17] = CvtDesc{Wo_b, pwb, nullptr, bias2, 1024, 1024, 0, 0, 0, 2};
  ca.d[18] = D1(e0b1,  bias01,       1024);
  ca.d[19] = D1(e1b1,  bias01+1024,  1024);
  cvt_all<<<20*64, 256, 0, stream>>>(ca);

  rmsnorm_k<<<NROWS, 256, 0, stream>>>(x, normw, A2);
  dwconv_k<<<(NROWS*DD)/256, 256, 0, stream>>>(A2, dwk, dwb, A2);

  // G2: fxu = xn @ [Wf_x;Wu_x;Win]^T + bias768   (f32)
  gemm_bt<0,0,0,0><<<64*6, 256, 0, stream>>>(A2, W_fxuwin, bias768, nullptr, nullptr,
                                             fxu, nullptr, nullptr, nullptr, nullptr, nullptr,
                                             NROWS, 768, 1024, 2048, 1024, 6, 1<<30);
  // fused: block0 = scan (m2all, newmem); blocks 1..512 = G34 (ybuf)
  scan_g34_k<<<513, 512, 0, stream>>>(fxu, W_fum, mem0, m2all,
                                      (float*)d_out + (size_t)NROWS*DD,
                                      A2, B2, bias2, x, ybuf);
  // G5: ybuf += m2 @ Wo_m^T ; ybf = bf16(ybuf)   (permuted rows t*4+b -> b*L+t)
  gemm_bt<0,3,1,0><<<64*8, 256, 0, stream>>>(m2all, W_om, nullptr, nullptr, nullptr,
                                             ybuf, ybf, nullptr, nullptr, nullptr, nullptr,
                                             NROWS, 1024, 256, 256, 256, 8, 1<<30);
  // experts stage 1 (fused): h01 = silu(ybf @ [e0w1;e1w1]^T + [e0b1;e1b1])
  gemm_bt<1,2,0,0><<<64*16, 256, 0, stream>>>(ybf, W_e01, bias01, nullptr, nullptr,
                                              h01, nullptr, nullptr, nullptr, nullptr, nullptr,
                                              NROWS, 2048, 1024, 1024, 1024, 16, 1<<30);
  // experts stage 2, both in ONE dispatch (DUAL pointer select)
  gemm_bt<0,2,0,1><<<64*16, 256, 0, stream>>>(h01, W_e0w2, e0b2, nullptr, nullptr,
                                              e0v, nullptr,
                                              h01+1024, W_e1w2, e1b2, e1v,
                                              NROWS, 1024, 1024, 2048, 1024, 8, 512);
  // router softmax + expert mix + final rmsnorm (in-place into ybuf / y2bf)
  combine_k<<<NROWS, 256, 0, stream>>>(ybuf, e0v, e1v, rw, rb, fnw, y2bf);
  // G10: hd = gelu(y2 @ down^T + down_b)   (bf16)
  gemm_bt<2,2,0,0><<<64*2, 256, 0, stream>>>(y2bf, W_down, dnb, nullptr, nullptr,
                                             hd, nullptr, nullptr, nullptr, nullptr, nullptr,
                                             NROWS, 256, 1024, 1024, 1024, 2, 1<<30);
  // G11: out = hd @ up^T + up_b + y2 + x
  gemm_bt<0,0,0,0><<<64*8, 256, 0, stream>>>(hd, W_up, upb, y2, x,
                                             (float*)d_out, nullptr, nullptr, nullptr, nullptr, nullptr,
                                             NROWS, 1024, 256, 256, 256, 8, 1<<30);
}

// Round 6
// 2481.356 us; speedup vs baseline: 1.0022x; 1.0022x over previous
//
#include <hip/hip_runtime.h>
#include <hip/hip_bf16.h>

#define DD 1024
#define MDD 256
#define LL 2048
#define BB 4
#define NROWS (BB*LL)   // 8192

typedef short bf16x8 __attribute__((ext_vector_type(8)));
typedef float f32x4 __attribute__((ext_vector_type(4)));
typedef int   i32x4 __attribute__((ext_vector_type(4)));

__device__ __forceinline__ short f2b(float x){
  __hip_bfloat16 h = __float2bfloat16(x);
  return *reinterpret_cast<short*>(&h);
}
__device__ __forceinline__ float b2f(short s){
  return __uint_as_float(((unsigned)(unsigned short)s) << 16);
}
__device__ __forceinline__ float frcp(float x){
#if __has_builtin(__builtin_amdgcn_rcpf)
  return __builtin_amdgcn_rcpf(x);
#else
  float r; asm("v_rcp_f32 %0, %1" : "=v"(r) : "v"(x)); return r;
#endif
}
__device__ __forceinline__ float fsigmoid(float x){
  return frcp(1.f + __expf(-x));
}
// select a[kg] without dynamic vector indexing (rule #20): 3 cndmask
__device__ __forceinline__ float sel4(f32x4 a, int kg){
  float lo = (kg & 1) ? a[1] : a[0];
  float hi = (kg & 1) ? a[3] : a[2];
  return (kg & 2) ? hi : lo;
}

// ---------------- fused weight conversion / bias prep (one launch) ----------------
struct CvtDesc {
  const float* src; const float* src2; short* dstb; float* dstf;
  int n, cols, sld, soff, dld, mode;
};
struct CvtArgs { CvtDesc d[20]; };

__global__ __launch_bounds__(256) void cvt_all(CvtArgs a){
  int di = blockIdx.x >> 6;
  CvtDesc d = a.d[di];
  int base = (blockIdx.x & 63)*256 + threadIdx.x;
  for (int i = base; i < d.n; i += 64*256){
    int r = i / d.cols, c = i - r*d.cols;
    float v = d.src[(size_t)r*d.sld + d.soff + c];
    if (d.mode == 2) v += d.src2[i];
    if (d.mode == 0) d.dstb[(size_t)r*d.dld + c] = f2b(v);
    else             d.dstf[i] = v;
  }
}

// ---------------- rmsnorm (f32 in -> bf16 out, strided out) ----------------
__global__ __launch_bounds__(256) void rmsnorm_k(const float* __restrict__ x,
                                                 const float* __restrict__ w,
                                                 short* __restrict__ xn){
  int row = blockIdx.x, tid = threadIdx.x;
  const float* xr = x + (size_t)row*DD;
  float4 v = *(const float4*)&xr[tid*4];
  float ss = v.x*v.x + v.y*v.y + v.z*v.z + v.w*v.w;
  __shared__ float red[256];
  red[tid] = ss; __syncthreads();
  for (int s = 128; s > 0; s >>= 1){ if (tid < s) red[tid] += red[tid+s]; __syncthreads(); }
  float scale = rsqrtf(red[0]/(float)DD + 1e-6f);
  const float* wr = w + tid*4;
  short4 o;
  o.x = f2b(v.x*wr[0]*scale); o.y = f2b(v.y*wr[1]*scale);
  o.z = f2b(v.z*wr[2]*scale); o.w = f2b(v.w*wr[3]*scale);
  *(short4*)&xn[(size_t)row*2048 + tid*4] = o;
}

// ---------------- depthwise causal conv K=5 (strided in/out: A2 layout) ----------------
__global__ __launch_bounds__(256) void dwconv_k(const short* __restrict__ xnA,
                                                const float* __restrict__ dwk,
                                                const float* __restrict__ dwb,
                                                short* __restrict__ xcA){
  size_t i = (size_t)blockIdx.x*256 + threadIdx.x;  // over NROWS*DD
  int d = (int)(i & (DD-1));
  int l = (int)((i >> 10) & (LL-1));
  int b = (int)(i >> 21);
  float acc = dwb[d];
  const float* kk = dwk + d*5;
  #pragma unroll
  for (int k = 0; k < 5; ++k){
    int ll = l + k - 4;
    if (ll >= 0) acc += b2f(xnA[((size_t)(b*LL + ll))*2048 + d]) * kk[k];
  }
  xcA[((size_t)(b*LL + l))*2048 + 1024 + d] = f2b(acc);
}

// ---------------- generic bf16 MFMA GEMM: C = act(A @ Bw^T + bias) (+adds) ----------------
// OUTMODE: 0=f32 store, 1=f32 accumulate, 2=bf16 store, 3=f32 accumulate + bf16 2nd out.
// ACT: 0 none, 1 silu, 2 exact gelu. DUAL: blocks >= nsplit use the _b pointer set.
template<int ACT, int OUTMODE, int PERMUTE, int DUAL>
__global__ __launch_bounds__(256) void gemm_bt(
    const short* __restrict__ A, const short* __restrict__ Bw,
    const float* __restrict__ bias, const float* __restrict__ add0,
    const float* __restrict__ add1, void* __restrict__ Cout, short* __restrict__ Cout2,
    const short* A_b, const short* Bw_b, const float* bias_b, void* Cout_b,
    int M, int N, int K, int lda, int ldb, int nbn, int nsplit){
  __shared__ __align__(16) short As[128*32];
  __shared__ __align__(16) short Bs[128*32];
  int bid = blockIdx.x;
  if (DUAL && bid >= nsplit){
    A = A_b; Bw = Bw_b; bias = bias_b; Cout = Cout_b; bid -= nsplit;
  }
  int bm = bid / nbn, bn = bid % nbn;
  int tid = threadIdx.x, lane = tid & 63, w = tid >> 6;
  int wm = (w >> 1)*64, wn = (w & 1)*64;
  const int r0 = lane & 15, kg = lane >> 4;

  f32x4 acc[4][4];
  #pragma unroll
  for (int i = 0; i < 4; ++i)
    #pragma unroll
    for (int j = 0; j < 4; ++j)
      #pragma unroll
      for (int r = 0; r < 4; ++r) acc[i][j][r] = 0.f;

  const int c0 = w*64 + lane;
  const int c1 = c0 + 256;
  const short* a0 = &A [(size_t)(bm*128 + (c0 >> 2))*lda + (c0 & 3)*8];
  const short* a1 = &A [(size_t)(bm*128 + (c1 >> 2))*lda + (c1 & 3)*8];
  const short* b0 = &Bw[(size_t)(bn*128 + (c0 >> 2))*ldb + (c0 & 3)*8];
  const short* b1 = &Bw[(size_t)(bn*128 + (c1 >> 2))*ldb + (c1 & 3)*8];

  for (int k0 = 0; k0 < K; k0 += 32){
    __builtin_amdgcn_global_load_lds((const __attribute__((address_space(1))) void*)(a0 + k0),
                                     (__attribute__((address_space(3))) void*)&As[w*512], 16, 0, 0);
    __builtin_amdgcn_global_load_lds((const __attribute__((address_space(1))) void*)(b0 + k0),
                                     (__attribute__((address_space(3))) void*)&Bs[w*512], 16, 0, 0);
    __builtin_amdgcn_global_load_lds((const __attribute__((address_space(1))) void*)(a1 + k0),
                                     (__attribute__((address_space(3))) void*)&As[2048 + w*512], 16, 0, 0);
    __builtin_amdgcn_global_load_lds((const __attribute__((address_space(1))) void*)(b1 + k0),
                                     (__attribute__((address_space(3))) void*)&Bs[2048 + w*512], 16, 0, 0);
    __syncthreads();
    bf16x8 av[4], bv[4];
    #pragma unroll
    for (int i = 0; i < 4; ++i) av[i] = *(const bf16x8*)&As[(wm + i*16 + r0)*32 + kg*8];
    #pragma unroll
    for (int j = 0; j < 4; ++j) bv[j] = *(const bf16x8*)&Bs[(wn + j*16 + r0)*32 + kg*8];
    #pragma unroll
    for (int i = 0; i < 4; ++i)
      #pragma unroll
      for (int j = 0; j < 4; ++j)
        acc[i][j] = __builtin_amdgcn_mfma_f32_16x16x32_bf16(av[i], bv[j], acc[i][j], 0, 0, 0);
    __syncthreads();
  }

  #pragma unroll
  for (int i = 0; i < 4; ++i){
    int grb = bm*128 + wm + i*16 + kg*4;
    #pragma unroll
    for (int j = 0; j < 4; ++j){
      int gc = bn*128 + wn + j*16 + r0;
      float bvv = bias ? bias[gc] : 0.f;
      #pragma unroll
      for (int r = 0; r < 4; ++r){
        int gr = grb + r;
        float v = acc[i][j][r] + bvv;
        if (ACT == 1) v = v / (1.f + __expf(-v));
        else if (ACT == 2) v = 0.5f*v*(1.f + erff(v*0.70710678118f));
        size_t orow = PERMUTE ? (size_t)((gr & 3)*LL + (gr >> 2)) : (size_t)gr;
        size_t oi = orow*(size_t)N + gc;
        if (add0) v += add0[oi];
        if (add1) v += add1[oi];
        if (OUTMODE == 0) ((float*)Cout)[oi] = v;
        else if (OUTMODE == 1) ((float*)Cout)[oi] += v;
        else if (OUTMODE == 2) ((short*)Cout)[oi] = f2b(v);
        else {
          float nv = ((float*)Cout)[oi] + v;
          ((float*)Cout)[oi] = nv;
          Cout2[oi] = f2b(nv);
        }
      }
    }
  }
}

// ---------------- fused: block 0 = sequential scan; blocks 1.. = G34 GEMM ----------------
__global__ __launch_bounds__(512, 2) void scan_g34_k(
    const float* __restrict__ fxu, const short* __restrict__ Wfu,
    const float* __restrict__ m0, short* __restrict__ m2all, float* __restrict__ newmem,
    const short* __restrict__ A2, const short* __restrict__ B2,
    const float* __restrict__ bias2, const float* __restrict__ xres,
    float* __restrict__ ybuf){
  __shared__ __align__(16) short lds[8192];   // 16KB; scan uses first 2176 shorts
  const int tid = threadIdx.x, lane = tid & 63, w = tid >> 6;
  const int r0 = lane & 15, kg = lane >> 4;

  if (blockIdx.x != 0){
    // ---------- G34 GEMM branch: 128x128 tile, 8 waves (wave = 64x32 subtile) ----------
    int bid = (int)blockIdx.x - 1;
    int bm = bid >> 3, bn = bid & 7;
    short* As = lds;          // [128][32]
    short* Bs = lds + 4096;
    int wm = (w >> 2)*64, wn = (w & 3)*32;
    f32x4 acc[4][2];
    #pragma unroll
    for (int i = 0; i < 4; ++i)
      #pragma unroll
      for (int j = 0; j < 2; ++j)
        #pragma unroll
        for (int r = 0; r < 4; ++r) acc[i][j][r] = 0.f;

    const int c = tid;  // chunk 0..511: row=c>>2, seg=c&3
    const short* ag = &A2[(size_t)(bm*128 + (c >> 2))*2048 + (c & 3)*8];
    const short* bg = &B2[(size_t)(bn*128 + (c >> 2))*2048 + (c & 3)*8];

    for (int k0 = 0; k0 < 2048; k0 += 32){
      __builtin_amdgcn_global_load_lds((const __attribute__((address_space(1))) void*)(ag + k0),
                                       (__attribute__((address_space(3))) void*)&As[w*512], 16, 0, 0);
      __builtin_amdgcn_global_load_lds((const __attribute__((address_space(1))) void*)(bg + k0),
                                       (__attribute__((address_space(3))) void*)&Bs[w*512], 16, 0, 0);
      __syncthreads();
      bf16x8 av[4], bv[2];
      #pragma unroll
      for (int i = 0; i < 4; ++i) av[i] = *(const bf16x8*)&As[(wm + i*16 + r0)*32 + kg*8];
      #pragma unroll
      for (int j = 0; j < 2; ++j) bv[j] = *(const bf16x8*)&Bs[(wn + j*16 + r0)*32 + kg*8];
      #pragma unroll
      for (int i = 0; i < 4; ++i)
        #pragma unroll
        for (int j = 0; j < 2; ++j)
          acc[i][j] = __builtin_amdgcn_mfma_f32_16x16x32_bf16(av[i], bv[j], acc[i][j], 0, 0, 0);
      __syncthreads();
    }
    #pragma unroll
    for (int i = 0; i < 4; ++i){
      int grb = bm*128 + wm + i*16 + kg*4;
      #pragma unroll
      for (int j = 0; j < 2; ++j){
        int gc = bn*128 + wn + j*16 + r0;
        float bvv = bias2[gc];
        #pragma unroll
        for (int r = 0; r < 4; ++r){
          size_t oi = (size_t)(grb + r)*1024 + gc;
          ybuf[oi] = acc[i][j][r] + bvv + xres[oi];
        }
      }
    }
    return;
  }

  // ---------- scan branch (block 0) ----------
  short* mA0 = lds;            // [4][272] x2 buffers
  short* mA1 = lds + 1088;
  const int j0 = w*32 + r0;

  // gate weights resident in VGPRs (128 VGPR): laundered BY VALUE through opaque asm so
  // the compiler can neither rematerialize the loads nor demote the array to scratch
  // (no address of bw is ever taken).
  bf16x8 bw[2][2][8];
  #pragma unroll
  for (int fu = 0; fu < 2; ++fu)
    #pragma unroll
    for (int p = 0; p < 2; ++p)
      #pragma unroll
      for (int kt = 0; kt < 8; ++kt){
        i32x4 ld = *(const i32x4*)&Wfu[(size_t)(fu*256 + w*32 + p*16 + r0)*256 + kt*32 + kg*8];
        asm volatile("" : "+v"(ld));
        bw[fu][p][kt] = __builtin_bit_cast(bf16x8, ld);
      }

  float m_reg0 = m0[kg*256 + j0];
  float m_reg1 = m0[kg*256 + j0 + 16];

  // step-t f/u raw (ready), step-t xm (ready), step-(t+1) x raw (in flight)
  float cf0, cf1, cu0, cu1, xmc0, xmc1, nx0, nx1;
  {
    size_t b0 = (size_t)kg*LL*768;
    cf0 = fxu[b0 + j0];        cf1 = fxu[b0 + j0 + 16];
    cu0 = fxu[b0 + 256 + j0];  cu1 = fxu[b0 + 256 + j0 + 16];
    float tx0 = fxu[b0 + 512 + j0], tx1 = fxu[b0 + 512 + j0 + 16];
    xmc0 = tx0*fsigmoid(tx0);  xmc1 = tx1*fsigmoid(tx1);
    size_t b1 = b0 + 768;
    nx0 = fxu[b1 + 512 + j0];  nx1 = fxu[b1 + 512 + j0 + 16];
  }
  mA0[kg*272 + j0]      = f2b(m_reg0);
  mA0[kg*272 + j0 + 16] = f2b(m_reg1);
  __syncthreads();

  // prologue: issue A-fragment reads for t=0
  bf16x8 af[8];
  #pragma unroll
  for (int kt = 0; kt < 8; ++kt)
    af[kt] = *(const bf16x8*)&mA0[(r0 & 3)*272 + kt*32 + kg*8];

  for (int t = 0; t < LL; ++t){
    short* man = (t & 1) ? mA0 : mA1;

    // next-step xm: depends only on nx (issued >=1 full step ago) -> overlaps MFMA phase
    float xmn0 = nx0*fsigmoid(nx0);
    float xmn1 = nx1*fsigmoid(nx1);

    __builtin_amdgcn_s_setprio(1);
    f32x4 aF0 = {0.f,0.f,0.f,0.f}, aF1 = {0.f,0.f,0.f,0.f};
    f32x4 aU0 = {0.f,0.f,0.f,0.f}, aU1 = {0.f,0.f,0.f,0.f};
    #pragma unroll
    for (int kt = 0; kt < 8; ++kt){
      aF0 = __builtin_amdgcn_mfma_f32_16x16x32_bf16(af[kt], bw[0][0][kt], aF0, 0, 0, 0);
      aF1 = __builtin_amdgcn_mfma_f32_16x16x32_bf16(af[kt], bw[0][1][kt], aF1, 0, 0, 0);
      aU0 = __builtin_amdgcn_mfma_f32_16x16x32_bf16(af[kt], bw[1][0][kt], aU0, 0, 0, 0);
      aU1 = __builtin_amdgcn_mfma_f32_16x16x32_bf16(af[kt], bw[1][1][kt], aU1, 0, 0, 0);
    }
    __builtin_amdgcn_s_setprio(0);

    float gF0 = sel4(aF0, kg), gF1 = sel4(aF1, kg);
    float gU0 = sel4(aU0, kg), gU1 = sel4(aU1, kg);

    float f0 = fsigmoid(gF0 + cf0);
    float f1 = fsigmoid(gF1 + cf1);
    float u0 = fsigmoid(gU0 + cu0);
    float u1 = fsigmoid(gU1 + cu1);
    m_reg0 = f0*m_reg0 + u0*xmc0;
    m_reg1 = f1*m_reg1 + u1*xmc1;
    short mb0 = f2b(m_reg0), mb1 = f2b(m_reg1);

    // publish m_t into the other buffer; only LDS must drain before barrier
    man[kg*272 + j0]      = mb0;
    man[kg*272 + j0 + 16] = mb1;
    asm volatile("s_waitcnt lgkmcnt(0)" ::: "memory");
    __builtin_amdgcn_sched_barrier(0);
    __builtin_amdgcn_s_barrier();
    __builtin_amdgcn_sched_barrier(0);

    // post-barrier: issue next step's A-fragment reads FIRST (critical path) ...
    if (t + 1 < LL){
      #pragma unroll
      for (int kt = 0; kt < 8; ++kt)
        af[kt] = *(const bf16x8*)&man[(r0 & 3)*272 + kt*32 + kg*8];
    }
    __builtin_amdgcn_sched_barrier(0);

    // ... then hide the global stores + prefetch issue under the ds_read latency
    m2all[(size_t)(t*4 + kg)*256 + j0]      = mb0;
    m2all[(size_t)(t*4 + kg)*256 + j0 + 16] = mb1;

    xmc0 = xmn0; xmc1 = xmn1;
    int t1 = (t + 1 < LL) ? t + 1 : t;
    int t2 = (t + 2 < LL) ? t + 2 : t;
    size_t bfu = ((size_t)kg*LL + t1)*768;
    size_t bx  = ((size_t)kg*LL + t2)*768;
    cf0 = fxu[bfu + j0];        cf1 = fxu[bfu + j0 + 16];
    cu0 = fxu[bfu + 256 + j0];  cu1 = fxu[bfu + 256 + j0 + 16];
    nx0 = fxu[bx + 512 + j0];   nx1 = fxu[bx + 512 + j0 + 16];
  }

  newmem[kg*256 + j0]      = m_reg0;
  newmem[kg*256 + j0 + 16] = m_reg1;
}

// ---------------- router + expert combine + final rmsnorm ----------------
__global__ __launch_bounds__(256) void combine_k(
    float* __restrict__ y, const short* __restrict__ e0, const short* __restrict__ e1,
    const float* __restrict__ rw, const float* __restrict__ rb,
    const float* __restrict__ fw, short* __restrict__ y2bf){
  int row = blockIdx.x, tid = threadIdx.x;
  size_t base = (size_t)row*DD + tid*4;
  float4 vy = *(const float4*)&y[base];
  short4 s0 = *(const short4*)&e0[base];
  short4 s1 = *(const short4*)&e1[base];
  float4 w0 = *(const float4*)&rw[tid*4];
  float4 w1 = *(const float4*)&rw[DD + tid*4];
  float d0 = vy.x*w0.x + vy.y*w0.y + vy.z*w0.z + vy.w*w0.w;
  float d1 = vy.x*w1.x + vy.y*w1.y + vy.z*w1.z + vy.w*w1.w;
  __shared__ float redA[256], redB[256];
  redA[tid] = d0; redB[tid] = d1; __syncthreads();
  for (int s = 128; s > 0; s >>= 1){
    if (tid < s){ redA[tid] += redA[tid+s]; redB[tid] += redB[tid+s]; }
    __syncthreads();
  }
  float l0 = redA[0] + rb[0], l1 = redB[0] + rb[1];
  float p0 = 1.f/(1.f + __expf(l1 - l0));
  float p1 = 1.f - p0;
  float c0 = vy.x + p0*b2f(s0.x) + p1*b2f(s1.x);
  float c1 = vy.y + p0*b2f(s0.y) + p1*b2f(s1.y);
  float c2 = vy.z + p0*b2f(s0.z) + p1*b2f(s1.z);
  float c3 = vy.w + p0*b2f(s0.w) + p1*b2f(s1.w);
  float ss = c0*c0 + c1*c1 + c2*c2 + c3*c3;
  __syncthreads();
  redA[tid] = ss; __syncthreads();
  for (int s = 128; s > 0; s >>= 1){
    if (tid < s) redA[tid] += redA[tid+s];
    __syncthreads();
  }
  float scale = rsqrtf(redA[0]/(float)DD + 1e-6f);
  const float* fwp = fw + tid*4;
  float o0 = c0*fwp[0]*scale, o1 = c1*fwp[1]*scale, o2 = c2*fwp[2]*scale, o3 = c3*fwp[3]*scale;
  float4 ov; ov.x = o0; ov.y = o1; ov.z = o2; ov.w = o3;
  *(float4*)&y[base] = ov;
  short4 ob; ob.x = f2b(o0); ob.y = f2b(o1); ob.z = f2b(o2); ob.w = f2b(o3);
  *(short4*)&y2bf[base] = ob;
}

// ---------------- host ----------------
extern "C" void kernel_launch(void* const* d_in, const int* in_sizes, int n_in,
                              void* d_out, int out_size, void* d_ws, size_t ws_size,
                              hipStream_t stream){
  (void)in_sizes; (void)n_in; (void)out_size; (void)ws_size;
  const float* x     = (const float*)d_in[0];
  const float* mem0  = (const float*)d_in[1];
  const float* normw = (const float*)d_in[2];
  const float* dwk   = (const float*)d_in[3];
  const float* dwb   = (const float*)d_in[4];
  const float* pw    = (const float*)d_in[5];
  const float* pwb   = (const float*)d_in[6];
  const float* Win_w = (const float*)d_in[7];
  const float* Win_b = (const float*)d_in[8];
  const float* Wf_w  = (const float*)d_in[9];
  const float* Wf_b  = (const float*)d_in[10];
  const float* Wu_w  = (const float*)d_in[11];
  const float* Wu_b  = (const float*)d_in[12];
  const float* Wo_w  = (const float*)d_in[13];
  const float* Wo_b  = (const float*)d_in[14];
  const float* rw    = (const float*)d_in[15];
  const float* rb    = (const float*)d_in[16];
  const float* e0w1  = (const float*)d_in[17];
  const float* e0b1  = (const float*)d_in[18];
  const float* e0w2  = (const float*)d_in[19];
  const float* e0b2  = (const float*)d_in[20];
  const float* e1w1  = (const float*)d_in[21];
  const float* e1b1  = (const float*)d_in[22];
  const float* e1w2  = (const float*)d_in[23];
  const float* e1b2  = (const float*)d_in[24];
  const float* fnw   = (const float*)d_in[25];
  const float* dnw   = (const float*)d_in[26];
  const float* dnb   = (const float*)d_in[27];
  const float* upw   = (const float*)d_in[28];
  const float* upb   = (const float*)d_in[29];

  char* ws = (char*)d_ws;
  size_t off = 0;
  auto alloc = [&](size_t bytes)->char*{
    char* p = ws + off; off += (bytes + 255) & ~(size_t)255; return p;
  };
  short* A2       = (short*)alloc((size_t)NROWS*2048*2);   // [xn | xc] bf16
  short* B2       = (short*)alloc((size_t)1024*2048*2);    // [Wo_x | pw] bf16
  short* W_fxuwin = (short*)alloc((size_t)768*1024*2);
  short* W_fum    = (short*)alloc((size_t)512*256*2);
  short* W_om     = (short*)alloc((size_t)1024*256*2);
  short* W_e01    = (short*)alloc((size_t)2048*1024*2);    // [e0w1 ; e1w1]
  short* W_e0w2   = (short*)alloc((size_t)1024*1024*2);
  short* W_e1w2   = (short*)alloc((size_t)1024*1024*2);
  short* W_down   = (short*)alloc((size_t)256*1024*2);
  short* W_up     = (short*)alloc((size_t)1024*256*2);
  float* bias768  = (float*)alloc(768*4);
  float* bias2    = (float*)alloc(1024*4);
  float* bias01   = (float*)alloc(2048*4);
  float* fxu      = (float*)alloc((size_t)NROWS*768*4);
  float* ybuf     = (float*)alloc((size_t)NROWS*DD*4);
  short* m2all    = (short*)alloc((size_t)NROWS*MDD*2);
  short* ybf      = (short*)alloc((size_t)NROWS*DD*2);
  short* e0v      = (short*)alloc((size_t)NROWS*DD*2);
  short* e1v      = (short*)alloc((size_t)NROWS*DD*2);
  short* h01      = (short*)alloc((size_t)NROWS*2048*2);   // [h0 | h1]
  short* hd = m2all;   // m2all dead after G5
  short* y2bf = ybf;   // ybf dead after expert first GEMM
  float* y2   = ybuf;  // in-place rmsnorm

  // ---- one fused weight-conversion launch (20 descriptors x 64 blocks) ----
  CvtArgs ca;
  auto D0 = [&](const float* s, short* db, int rows, int cols, int sld, int soff, int dld){
    return CvtDesc{s, nullptr, db, nullptr, rows*cols, cols, sld, soff, dld, 0};
  };
  auto D1 = [&](const float* s, float* df, int n){
    return CvtDesc{s, nullptr, nullptr, df, n, n, 0, 0, 0, 1};
  };
  ca.d[0]  = D0(Wo_w,  B2,                1024, 1024, 1280, 0,    2048);
  ca.d[1]  = D0(pw,    B2+1024,           1024, 1024, 1024, 0,    2048);
  ca.d[2]  = D0(Wf_w,  W_fxuwin,           256, 1024, 1280, 0,    1024);
  ca.d[3]  = D0(Wu_w,  W_fxuwin+256*1024,  256, 1024, 1280, 0,    1024);
  ca.d[4]  = D0(Win_w, W_fxuwin+512*1024,  256, 1024, 1024, 0,    1024);
  ca.d[5]  = D0(Wf_w,  W_fum,              256,  256, 1280, 1024, 256);
  ca.d[6]  = D0(Wu_w,  W_fum+256*256,      256,  256, 1280, 1024, 256);
  ca.d[7]  = D0(Wo_w,  W_om,              1024,  256, 1280, 1024, 256);
  ca.d[8]  = D0(e0w1,  W_e01,             1024, 1024, 1024, 0,    1024);
  ca.d[9]  = D0(e1w1,  W_e01+1024*1024,   1024, 1024, 1024, 0,    1024);
  ca.d[10] = D0(e0w2,  W_e0w2,            1024, 1024, 1024, 0,    1024);
  ca.d[11] = D0(e1w2,  W_e1w2,            1024, 1024, 1024, 0,    1024);
  ca.d[12] = D0(dnw,   W_down,             256, 1024, 1024, 0,    1024);
  ca.d[13] = D0(upw,   W_up,              1024,  256,  256, 0,    256);
  ca.d[14] = D1(Wf_b,  bias768,       256);
  ca.d[15] = D1(Wu_b,  bias768+256,   256);
  ca.d[16] = D1(Win_b, bias768+512,   256);
  ca.d[17] = CvtDesc{Wo_b, pwb, nullptr, bias2, 1024, 1024, 0, 0, 0, 2};
  ca.d[18] = D1(e0b1,  bias01,       1024);
  ca.d[19] = D1(e1b1,  bias01+1024,  1024);
  cvt_all<<<20*64, 256, 0, stream>>>(ca);

  rmsnorm_k<<<NROWS, 256, 0, stream>>>(x, normw, A2);
  dwconv_k<<<(NROWS*DD)/256, 256, 0, stream>>>(A2, dwk, dwb, A2);

  // G2: fxu = xn @ [Wf_x;Wu_x;Win]^T + bias768   (f32)
  gemm_bt<0,0,0,0><<<64*6, 256, 0, stream>>>(A2, W_fxuwin, bias768, nullptr, nullptr,
                                             fxu, nullptr, nullptr, nullptr, nullptr, nullptr,
                                             NROWS, 768, 1024, 2048, 1024, 6, 1<<30);
  // fused: block0 = scan (m2all, newmem); blocks 1..512 = G34 (ybuf)
  scan_g34_k<<<513, 512, 0, stream>>>(fxu, W_fum, mem0, m2all,
                                      (float*)d_out + (size_t)NROWS*DD,
                                      A2, B2, bias2, x, ybuf);
  // G5: ybuf += m2 @ Wo_m^T ; ybf = bf16(ybuf)   (permuted rows t*4+b -> b*L+t)
  gemm_bt<0,3,1,0><<<64*8, 256, 0, stream>>>(m2all, W_om, nullptr, nullptr, nullptr,
                                             ybuf, ybf, nullptr, nullptr, nullptr, nullptr,
                                             NROWS, 1024, 256, 256, 256, 8, 1<<30);
  // experts stage 1 (fused): h01 = silu(ybf @ [e0w1;e1w1]^T + [e0b1;e1b1])
  gemm_bt<1,2,0,0><<<64*16, 256, 0, stream>>>(ybf, W_e01, bias01, nullptr, nullptr,
                                              h01, nullptr, nullptr, nullptr, nullptr, nullptr,
                                              NROWS, 2048, 1024, 1024, 1024, 16, 1<<30);
  // experts stage 2, both in ONE dispatch (DUAL pointer select)
  gemm_bt<0,2,0,1><<<64*16, 256, 0, stream>>>(h01, W_e0w2, e0b2, nullptr, nullptr,
                                              e0v, nullptr,
                                              h01+1024, W_e1w2, e1b2, e1v,
                                              NROWS, 1024, 1024, 2048, 1024, 8, 512);
  // router softmax + expert mix + final rmsnorm (in-place into ybuf / y2bf)
  combine_k<<<NROWS, 256, 0, stream>>>(ybuf, e0v, e1v, rw, rb, fnw, y2bf);
  // G10: hd = gelu(y2 @ down^T + down_b)   (bf16)
  gemm_bt<2,2,0,0><<<64*2, 256, 0, stream>>>(y2bf, W_down, dnb, nullptr, nullptr,
                                             hd, nullptr, nullptr, nullptr, nullptr, nullptr,
                                             NROWS, 256, 1024, 1024, 1024, 2, 1<<30);
  // G11: out = hd @ up^T + up_b + y2 + x
  gemm_bt<0,0,0,0><<<64*8, 256, 0, stream>>>(hd, W_up, upb, y2, x,
                                             (float*)d_out, nullptr, nullptr, nullptr, nullptr, nullptr,
                                             NROWS, 1024, 256, 256, 256, 8, 1<<30);
}

// Round 7
// 1947.185 us; speedup vs baseline: 1.2771x; 1.2743x over previous
//
#include <hip/hip_runtime.h>
#include <hip/hip_bf16.h>

#define DD 1024
#define MDD 256
#define LL 2048
#define BB 4
#define NROWS (BB*LL)   // 8192

typedef short bf16x8 __attribute__((ext_vector_type(8)));
typedef float f32x4 __attribute__((ext_vector_type(4)));
typedef int   i32x4 __attribute__((ext_vector_type(4)));

__device__ __forceinline__ short f2b(float x){
  __hip_bfloat16 h = __float2bfloat16(x);
  return *reinterpret_cast<short*>(&h);
}
__device__ __forceinline__ float b2f(short s){
  return __uint_as_float(((unsigned)(unsigned short)s) << 16);
}
__device__ __forceinline__ float frcp(float x){
#if __has_builtin(__builtin_amdgcn_rcpf)
  return __builtin_amdgcn_rcpf(x);
#else
  float r; asm("v_rcp_f32 %0, %1" : "=v"(r) : "v"(x)); return r;
#endif
}
__device__ __forceinline__ float fsigmoid(float x){
  return frcp(1.f + __expf(-x));
}
// select a[kg] without dynamic vector indexing (rule #20): 3 cndmask
__device__ __forceinline__ float sel4(f32x4 a, int kg){
  float lo = (kg & 1) ? a[1] : a[0];
  float hi = (kg & 1) ? a[3] : a[2];
  return (kg & 2) ? hi : lo;
}

// ---------------- fused weight conversion / bias prep (one launch) ----------------
struct CvtDesc {
  const float* src; const float* src2; short* dstb; float* dstf;
  int n, cols, sld, soff, dld, mode;
};
struct CvtArgs { CvtDesc d[20]; };

__global__ __launch_bounds__(256) void cvt_all(CvtArgs a){
  int di = blockIdx.x >> 6;
  CvtDesc d = a.d[di];
  int base = (blockIdx.x & 63)*256 + threadIdx.x;
  for (int i = base; i < d.n; i += 64*256){
    int r = i / d.cols, c = i - r*d.cols;
    float v = d.src[(size_t)r*d.sld + d.soff + c];
    if (d.mode == 2) v += d.src2[i];
    if (d.mode == 0) d.dstb[(size_t)r*d.dld + c] = f2b(v);
    else             d.dstf[i] = v;
  }
}

// ---------------- rmsnorm (f32 in -> bf16 out, strided out) ----------------
__global__ __launch_bounds__(256) void rmsnorm_k(const float* __restrict__ x,
                                                 const float* __restrict__ w,
                                                 short* __restrict__ xn){
  int row = blockIdx.x, tid = threadIdx.x;
  const float* xr = x + (size_t)row*DD;
  float4 v = *(const float4*)&xr[tid*4];
  float ss = v.x*v.x + v.y*v.y + v.z*v.z + v.w*v.w;
  __shared__ float red[256];
  red[tid] = ss; __syncthreads();
  for (int s = 128; s > 0; s >>= 1){ if (tid < s) red[tid] += red[tid+s]; __syncthreads(); }
  float scale = rsqrtf(red[0]/(float)DD + 1e-6f);
  const float* wr = w + tid*4;
  short4 o;
  o.x = f2b(v.x*wr[0]*scale); o.y = f2b(v.y*wr[1]*scale);
  o.z = f2b(v.z*wr[2]*scale); o.w = f2b(v.w*wr[3]*scale);
  *(short4*)&xn[(size_t)row*2048 + tid*4] = o;
}

// ---------------- depthwise causal conv K=5 (strided in/out: A2 layout) ----------------
__global__ __launch_bounds__(256) void dwconv_k(const short* __restrict__ xnA,
                                                const float* __restrict__ dwk,
                                                const float* __restrict__ dwb,
                                                short* __restrict__ xcA){
  size_t i = (size_t)blockIdx.x*256 + threadIdx.x;  // over NROWS*DD
  int d = (int)(i & (DD-1));
  int l = (int)((i >> 10) & (LL-1));
  int b = (int)(i >> 21);
  float acc = dwb[d];
  const float* kk = dwk + d*5;
  #pragma unroll
  for (int k = 0; k < 5; ++k){
    int ll = l + k - 4;
    if (ll >= 0) acc += b2f(xnA[((size_t)(b*LL + ll))*2048 + d]) * kk[k];
  }
  xcA[((size_t)(b*LL + l))*2048 + 1024 + d] = f2b(acc);
}

// ---------------- generic bf16 MFMA GEMM: C = act(A @ Bw^T + bias) (+adds) ----------------
// OUTMODE: 0=f32 store, 1=f32 accumulate, 2=bf16 store, 3=f32 accumulate + bf16 2nd out.
// ACT: 0 none, 1 silu, 2 exact gelu. DUAL: blocks >= nsplit use the _b pointer set.
template<int ACT, int OUTMODE, int PERMUTE, int DUAL>
__global__ __launch_bounds__(256) void gemm_bt(
    const short* __restrict__ A, const short* __restrict__ Bw,
    const float* __restrict__ bias, const float* __restrict__ add0,
    const float* __restrict__ add1, void* __restrict__ Cout, short* __restrict__ Cout2,
    const short* A_b, const short* Bw_b, const float* bias_b, void* Cout_b,
    int M, int N, int K, int lda, int ldb, int nbn, int nsplit){
  __shared__ __align__(16) short As[128*32];
  __shared__ __align__(16) short Bs[128*32];
  int bid = blockIdx.x;
  if (DUAL && bid >= nsplit){
    A = A_b; Bw = Bw_b; bias = bias_b; Cout = Cout_b; bid -= nsplit;
  }
  int bm = bid / nbn, bn = bid % nbn;
  int tid = threadIdx.x, lane = tid & 63, w = tid >> 6;
  int wm = (w >> 1)*64, wn = (w & 1)*64;
  const int r0 = lane & 15, kg = lane >> 4;

  f32x4 acc[4][4];
  #pragma unroll
  for (int i = 0; i < 4; ++i)
    #pragma unroll
    for (int j = 0; j < 4; ++j)
      #pragma unroll
      for (int r = 0; r < 4; ++r) acc[i][j][r] = 0.f;

  const int c0 = w*64 + lane;
  const int c1 = c0 + 256;
  const short* a0 = &A [(size_t)(bm*128 + (c0 >> 2))*lda + (c0 & 3)*8];
  const short* a1 = &A [(size_t)(bm*128 + (c1 >> 2))*lda + (c1 & 3)*8];
  const short* b0 = &Bw[(size_t)(bn*128 + (c0 >> 2))*ldb + (c0 & 3)*8];
  const short* b1 = &Bw[(size_t)(bn*128 + (c1 >> 2))*ldb + (c1 & 3)*8];

  for (int k0 = 0; k0 < K; k0 += 32){
    __builtin_amdgcn_global_load_lds((const __attribute__((address_space(1))) void*)(a0 + k0),
                                     (__attribute__((address_space(3))) void*)&As[w*512], 16, 0, 0);
    __builtin_amdgcn_global_load_lds((const __attribute__((address_space(1))) void*)(b0 + k0),
                                     (__attribute__((address_space(3))) void*)&Bs[w*512], 16, 0, 0);
    __builtin_amdgcn_global_load_lds((const __attribute__((address_space(1))) void*)(a1 + k0),
                                     (__attribute__((address_space(3))) void*)&As[2048 + w*512], 16, 0, 0);
    __builtin_amdgcn_global_load_lds((const __attribute__((address_space(1))) void*)(b1 + k0),
                                     (__attribute__((address_space(3))) void*)&Bs[2048 + w*512], 16, 0, 0);
    __syncthreads();
    bf16x8 av[4], bv[4];
    #pragma unroll
    for (int i = 0; i < 4; ++i) av[i] = *(const bf16x8*)&As[(wm + i*16 + r0)*32 + kg*8];
    #pragma unroll
    for (int j = 0; j < 4; ++j) bv[j] = *(const bf16x8*)&Bs[(wn + j*16 + r0)*32 + kg*8];
    #pragma unroll
    for (int i = 0; i < 4; ++i)
      #pragma unroll
      for (int j = 0; j < 4; ++j)
        acc[i][j] = __builtin_amdgcn_mfma_f32_16x16x32_bf16(av[i], bv[j], acc[i][j], 0, 0, 0);
    __syncthreads();
  }

  #pragma unroll
  for (int i = 0; i < 4; ++i){
    int grb = bm*128 + wm + i*16 + kg*4;
    #pragma unroll
    for (int j = 0; j < 4; ++j){
      int gc = bn*128 + wn + j*16 + r0;
      float bvv = bias ? bias[gc] : 0.f;
      #pragma unroll
      for (int r = 0; r < 4; ++r){
        int gr = grb + r;
        float v = acc[i][j][r] + bvv;
        if (ACT == 1) v = v / (1.f + __expf(-v));
        else if (ACT == 2) v = 0.5f*v*(1.f + erff(v*0.70710678118f));
        size_t orow = PERMUTE ? (size_t)((gr & 3)*LL + (gr >> 2)) : (size_t)gr;
        size_t oi = orow*(size_t)N + gc;
        if (add0) v += add0[oi];
        if (add1) v += add1[oi];
        if (OUTMODE == 0) ((float*)Cout)[oi] = v;
        else if (OUTMODE == 1) ((float*)Cout)[oi] += v;
        else if (OUTMODE == 2) ((short*)Cout)[oi] = f2b(v);
        else {
          float nv = ((float*)Cout)[oi] + v;
          ((float*)Cout)[oi] = nv;
          Cout2[oi] = f2b(nv);
        }
      }
    }
  }
}

// ---------------- fused: block 0 = sequential scan; blocks 1.. = G34 GEMM ----------------
// waves_per_eu(2,2): pin occupancy to 2 waves/EU so the allocator gets a 256-VGPR
// budget and can keep the scan's gate weights register-resident.
__global__ __launch_bounds__(512) __attribute__((amdgpu_waves_per_eu(2, 2)))
void scan_g34_k(
    const float* __restrict__ fxu, const short* __restrict__ Wfu,
    const float* __restrict__ m0, short* __restrict__ m2all, float* __restrict__ newmem,
    const short* __restrict__ A2, const short* __restrict__ B2,
    const float* __restrict__ bias2, const float* __restrict__ xres,
    float* __restrict__ ybuf){
  __shared__ __align__(16) short lds[8192];   // 16KB; scan uses first 2176 shorts
  const int tid = threadIdx.x, lane = tid & 63, w = tid >> 6;
  const int r0 = lane & 15, kg = lane >> 4;

  if (blockIdx.x != 0){
    // ---------- G34 GEMM branch: 128x128 tile, 8 waves (wave = 64x32 subtile) ----------
    int bid = (int)blockIdx.x - 1;
    int bm = bid >> 3, bn = bid & 7;
    short* As = lds;          // [128][32]
    short* Bs = lds + 4096;
    int wm = (w >> 2)*64, wn = (w & 3)*32;
    f32x4 acc[4][2];
    #pragma unroll
    for (int i = 0; i < 4; ++i)
      #pragma unroll
      for (int j = 0; j < 2; ++j)
        #pragma unroll
        for (int r = 0; r < 4; ++r) acc[i][j][r] = 0.f;

    const int c = tid;  // chunk 0..511: row=c>>2, seg=c&3
    const short* ag = &A2[(size_t)(bm*128 + (c >> 2))*2048 + (c & 3)*8];
    const short* bg = &B2[(size_t)(bn*128 + (c >> 2))*2048 + (c & 3)*8];

    for (int k0 = 0; k0 < 2048; k0 += 32){
      __builtin_amdgcn_global_load_lds((const __attribute__((address_space(1))) void*)(ag + k0),
                                       (__attribute__((address_space(3))) void*)&As[w*512], 16, 0, 0);
      __builtin_amdgcn_global_load_lds((const __attribute__((address_space(1))) void*)(bg + k0),
                                       (__attribute__((address_space(3))) void*)&Bs[w*512], 16, 0, 0);
      __syncthreads();
      bf16x8 av[4], bv[2];
      #pragma unroll
      for (int i = 0; i < 4; ++i) av[i] = *(const bf16x8*)&As[(wm + i*16 + r0)*32 + kg*8];
      #pragma unroll
      for (int j = 0; j < 2; ++j) bv[j] = *(const bf16x8*)&Bs[(wn + j*16 + r0)*32 + kg*8];
      #pragma unroll
      for (int i = 0; i < 4; ++i)
        #pragma unroll
        for (int j = 0; j < 2; ++j)
          acc[i][j] = __builtin_amdgcn_mfma_f32_16x16x32_bf16(av[i], bv[j], acc[i][j], 0, 0, 0);
      __syncthreads();
    }
    #pragma unroll
    for (int i = 0; i < 4; ++i){
      int grb = bm*128 + wm + i*16 + kg*4;
      #pragma unroll
      for (int j = 0; j < 2; ++j){
        int gc = bn*128 + wn + j*16 + r0;
        float bvv = bias2[gc];
        #pragma unroll
        for (int r = 0; r < 4; ++r){
          size_t oi = (size_t)(grb + r)*1024 + gc;
          ybuf[oi] = acc[i][j][r] + bvv + xres[oi];
        }
      }
    }
    return;
  }

  // ---------- scan branch (block 0) ----------
  short* mA0 = lds;            // [4][272] x2 buffers
  short* mA1 = lds + 1088;
  const int j0 = w*32 + r0;

  // gate weights resident in VGPRs (128 VGPR): laundered BY VALUE through opaque asm
  // (no address of bw is ever formed, loads cannot be rematerialized; with the
  // waves_per_eu(2,2) 256-reg budget there is no pressure to spill).
  bf16x8 bw[2][2][8];
  #pragma unroll
  for (int fu = 0; fu < 2; ++fu)
    #pragma unroll
    for (int p = 0; p < 2; ++p)
      #pragma unroll
      for (int kt = 0; kt < 8; ++kt){
        i32x4 ld = *(const i32x4*)&Wfu[(size_t)(fu*256 + w*32 + p*16 + r0)*256 + kt*32 + kg*8];
        asm volatile("" : "+v"(ld));
        bw[fu][p][kt] = __builtin_bit_cast(bf16x8, ld);
      }

  float m_reg0 = m0[kg*256 + j0];
  float m_reg1 = m0[kg*256 + j0 + 16];

  // step-t f/u raw (ready), step-t xm (ready), step-(t+1) x raw (in flight)
  float cf0, cf1, cu0, cu1, xmc0, xmc1, nx0, nx1;
  {
    size_t b0 = (size_t)kg*LL*768;
    cf0 = fxu[b0 + j0];        cf1 = fxu[b0 + j0 + 16];
    cu0 = fxu[b0 + 256 + j0];  cu1 = fxu[b0 + 256 + j0 + 16];
    float tx0 = fxu[b0 + 512 + j0], tx1 = fxu[b0 + 512 + j0 + 16];
    xmc0 = tx0*fsigmoid(tx0);  xmc1 = tx1*fsigmoid(tx1);
    size_t b1 = b0 + 768;
    nx0 = fxu[b1 + 512 + j0];  nx1 = fxu[b1 + 512 + j0 + 16];
  }
  mA0[kg*272 + j0]      = f2b(m_reg0);
  mA0[kg*272 + j0 + 16] = f2b(m_reg1);
  __syncthreads();

  for (int t = 0; t < LL; ++t){
    const short* mac = (t & 1) ? mA1 : mA0;
    short*       man = (t & 1) ? mA0 : mA1;

    // A-fragments: row = batch (r0&3) -> 4-lane broadcast reads, conflict-lite
    bf16x8 af[8];
    #pragma unroll
    for (int kt = 0; kt < 8; ++kt)
      af[kt] = *(const bf16x8*)&mac[(r0 & 3)*272 + kt*32 + kg*8];

    // next-step xm: depends only on nx (issued >=1 full step ago) -> overlaps MFMA phase
    float xmn0 = nx0*fsigmoid(nx0);
    float xmn1 = nx1*fsigmoid(nx1);

    __builtin_amdgcn_s_setprio(1);
    f32x4 aF0 = {0.f,0.f,0.f,0.f}, aF1 = {0.f,0.f,0.f,0.f};
    f32x4 aU0 = {0.f,0.f,0.f,0.f}, aU1 = {0.f,0.f,0.f,0.f};
    #pragma unroll
    for (int kt = 0; kt < 8; ++kt){
      aF0 = __builtin_amdgcn_mfma_f32_16x16x32_bf16(af[kt], bw[0][0][kt], aF0, 0, 0, 0);
      aF1 = __builtin_amdgcn_mfma_f32_16x16x32_bf16(af[kt], bw[0][1][kt], aF1, 0, 0, 0);
      aU0 = __builtin_amdgcn_mfma_f32_16x16x32_bf16(af[kt], bw[1][0][kt], aU0, 0, 0, 0);
      aU1 = __builtin_amdgcn_mfma_f32_16x16x32_bf16(af[kt], bw[1][1][kt], aU1, 0, 0, 0);
    }
    __builtin_amdgcn_s_setprio(0);

    // acc reg r holds batch r (rows duplicated mod 4) -> in-register gate select
    float gF0 = sel4(aF0, kg), gF1 = sel4(aF1, kg);
    float gU0 = sel4(aU0, kg), gU1 = sel4(aU1, kg);

    float f0 = fsigmoid(gF0 + cf0);
    float f1 = fsigmoid(gF1 + cf1);
    float u0 = fsigmoid(gU0 + cu0);
    float u1 = fsigmoid(gU1 + cu1);
    m_reg0 = f0*m_reg0 + u0*xmc0;
    m_reg1 = f1*m_reg1 + u1*xmc1;
    short mb0 = f2b(m_reg0), mb1 = f2b(m_reg1);

    // stream out m_t (global stores stay in flight across the raw barrier)
    m2all[(size_t)(t*4 + kg)*256 + j0]      = mb0;
    m2all[(size_t)(t*4 + kg)*256 + j0 + 16] = mb1;

    // rotate xm pipeline; prefetch f/u for t+1, x for t+2
    xmc0 = xmn0; xmc1 = xmn1;
    int t1 = (t + 1 < LL) ? t + 1 : t;
    int t2 = (t + 2 < LL) ? t + 2 : t;
    size_t bfu = ((size_t)kg*LL + t1)*768;
    size_t bx  = ((size_t)kg*LL + t2)*768;
    cf0 = fxu[bfu + j0];        cf1 = fxu[bfu + j0 + 16];
    cu0 = fxu[bfu + 256 + j0];  cu1 = fxu[bfu + 256 + j0 + 16];
    nx0 = fxu[bx + 512 + j0];   nx1 = fxu[bx + 512 + j0 + 16];

    // publish m_t into the other buffer; only LDS must drain before barrier
    man[kg*272 + j0]      = mb0;
    man[kg*272 + j0 + 16] = mb1;
    asm volatile("s_waitcnt lgkmcnt(0)" ::: "memory");
    __builtin_amdgcn_sched_barrier(0);
    __builtin_amdgcn_s_barrier();
    __builtin_amdgcn_sched_barrier(0);
  }

  newmem[kg*256 + j0]      = m_reg0;
  newmem[kg*256 + j0 + 16] = m_reg1;
}

// ---------------- router + expert combine + final rmsnorm ----------------
__global__ __launch_bounds__(256) void combine_k(
    float* __restrict__ y, const short* __restrict__ e0, const short* __restrict__ e1,
    const float* __restrict__ rw, const float* __restrict__ rb,
    const float* __restrict__ fw, short* __restrict__ y2bf){
  int row = blockIdx.x, tid = threadIdx.x;
  size_t base = (size_t)row*DD + tid*4;
  float4 vy = *(const float4*)&y[base];
  short4 s0 = *(const short4*)&e0[base];
  short4 s1 = *(const short4*)&e1[base];
  float4 w0 = *(const float4*)&rw[tid*4];
  float4 w1 = *(const float4*)&rw[DD + tid*4];
  float d0 = vy.x*w0.x + vy.y*w0.y + vy.z*w0.z + vy.w*w0.w;
  float d1 = vy.x*w1.x + vy.y*w1.y + vy.z*w1.z + vy.w*w1.w;
  __shared__ float redA[256], redB[256];
  redA[tid] = d0; redB[tid] = d1; __syncthreads();
  for (int s = 128; s > 0; s >>= 1){
    if (tid < s){ redA[tid] += redA[tid+s]; redB[tid] += redB[tid+s]; }
    __syncthreads();
  }
  float l0 = redA[0] + rb[0], l1 = redB[0] + rb[1];
  float p0 = 1.f/(1.f + __expf(l1 - l0));
  float p1 = 1.f - p0;
  float c0 = vy.x + p0*b2f(s0.x) + p1*b2f(s1.x);
  float c1 = vy.y + p0*b2f(s0.y) + p1*b2f(s1.y);
  float c2 = vy.z + p0*b2f(s0.z) + p1*b2f(s1.z);
  float c3 = vy.w + p0*b2f(s0.w) + p1*b2f(s1.w);
  float ss = c0*c0 + c1*c1 + c2*c2 + c3*c3;
  __syncthreads();
  redA[tid] = ss; __syncthreads();
  for (int s = 128; s > 0; s >>= 1){
    if (tid < s) redA[tid] += redA[tid+s];
    __syncthreads();
  }
  float scale = rsqrtf(redA[0]/(float)DD + 1e-6f);
  const float* fwp = fw + tid*4;
  float o0 = c0*fwp[0]*scale, o1 = c1*fwp[1]*scale, o2 = c2*fwp[2]*scale, o3 = c3*fwp[3]*scale;
  float4 ov; ov.x = o0; ov.y = o1; ov.z = o2; ov.w = o3;
  *(float4*)&y[base] = ov;
  short4 ob; ob.x = f2b(o0); ob.y = f2b(o1); ob.z = f2b(o2); ob.w = f2b(o3);
  *(short4*)&y2bf[base] = ob;
}

// ---------------- host ----------------
extern "C" void kernel_launch(void* const* d_in, const int* in_sizes, int n_in,
                              void* d_out, int out_size, void* d_ws, size_t ws_size,
                              hipStream_t stream){
  (void)in_sizes; (void)n_in; (void)out_size; (void)ws_size;
  const float* x     = (const float*)d_in[0];
  const float* mem0  = (const float*)d_in[1];
  const float* normw = (const float*)d_in[2];
  const float* dwk   = (const float*)d_in[3];
  const float* dwb   = (const float*)d_in[4];
  const float* pw    = (const float*)d_in[5];
  const float* pwb   = (const float*)d_in[6];
  const float* Win_w = (const float*)d_in[7];
  const float* Win_b = (const float*)d_in[8];
  const float* Wf_w  = (const float*)d_in[9];
  const float* Wf_b  = (const float*)d_in[10];
  const float* Wu_w  = (const float*)d_in[11];
  const float* Wu_b  = (const float*)d_in[12];
  const float* Wo_w  = (const float*)d_in[13];
  const float* Wo_b  = (const float*)d_in[14];
  const float* rw    = (const float*)d_in[15];
  const float* rb    = (const float*)d_in[16];
  const float* e0w1  = (const float*)d_in[17];
  const float* e0b1  = (const float*)d_in[18];
  const float* e0w2  = (const float*)d_in[19];
  const float* e0b2  = (const float*)d_in[20];
  const float* e1w1  = (const float*)d_in[21];
  const float* e1b1  = (const float*)d_in[22];
  const float* e1w2  = (const float*)d_in[23];
  const float* e1b2  = (const float*)d_in[24];
  const float* fnw   = (const float*)d_in[25];
  const float* dnw   = (const float*)d_in[26];
  const float* dnb   = (const float*)d_in[27];
  const float* upw   = (const float*)d_in[28];
  const float* upb   = (const float*)d_in[29];

  char* ws = (char*)d_ws;
  size_t off = 0;
  auto alloc = [&](size_t bytes)->char*{
    char* p = ws + off; off += (bytes + 255) & ~(size_t)255; return p;
  };
  short* A2       = (short*)alloc((size_t)NROWS*2048*2);   // [xn | xc] bf16
  short* B2       = (short*)alloc((size_t)1024*2048*2);    // [Wo_x | pw] bf16
  short* W_fxuwin = (short*)alloc((size_t)768*1024*2);
  short* W_fum    = (short*)alloc((size_t)512*256*2);
  short* W_om     = (short*)alloc((size_t)1024*256*2);
  short* W_e01    = (short*)alloc((size_t)2048*1024*2);    // [e0w1 ; e1w1]
  short* W_e0w2   = (short*)alloc((size_t)1024*1024*2);
  short* W_e1w2   = (short*)alloc((size_t)1024*1024*2);
  short* W_down   = (short*)alloc((size_t)256*1024*2);
  short* W_up     = (short*)alloc((size_t)1024*256*2);
  float* bias768  = (float*)alloc(768*4);
  float* bias2    = (float*)alloc(1024*4);
  float* bias01   = (float*)alloc(2048*4);
  float* fxu      = (float*)alloc((size_t)NROWS*768*4);
  float* ybuf     = (float*)alloc((size_t)NROWS*DD*4);
  short* m2all    = (short*)alloc((size_t)NROWS*MDD*2);
  short* ybf      = (short*)alloc((size_t)NROWS*DD*2);
  short* e0v      = (short*)alloc((size_t)NROWS*DD*2);
  short* e1v      = (short*)alloc((size_t)NROWS*DD*2);
  short* h01      = (short*)alloc((size_t)NROWS*2048*2);   // [h0 | h1]
  short* hd = m2all;   // m2all dead after G5
  short* y2bf = ybf;   // ybf dead after expert first GEMM
  float* y2   = ybuf;  // in-place rmsnorm

  // ---- one fused weight-conversion launch (20 descriptors x 64 blocks) ----
  CvtArgs ca;
  auto D0 = [&](const float* s, short* db, int rows, int cols, int sld, int soff, int dld){
    return CvtDesc{s, nullptr, db, nullptr, rows*cols, cols, sld, soff, dld, 0};
  };
  auto D1 = [&](const float* s, float* df, int n){
    return CvtDesc{s, nullptr, nullptr, df, n, n, 0, 0, 0, 1};
  };
  ca.d[0]  = D0(Wo_w,  B2,                1024, 1024, 1280, 0,    2048);
  ca.d[1]  = D0(pw,    B2+1024,           1024, 1024, 1024, 0,    2048);
  ca.d[2]  = D0(Wf_w,  W_fxuwin,           256, 1024, 1280, 0,    1024);
  ca.d[3]  = D0(Wu_w,  W_fxuwin+256*1024,  256, 1024, 1280, 0,    1024);
  ca.d[4]  = D0(Win_w, W_fxuwin+512*1024,  256, 1024, 1024, 0,    1024);
  ca.d[5]  = D0(Wf_w,  W_fum,              256,  256, 1280, 1024, 256);
  ca.d[6]  = D0(Wu_w,  W_fum+256*256,      256,  256, 1280, 1024, 256);
  ca.d[7]  = D0(Wo_w,  W_om,              1024,  256, 1280, 1024, 256);
  ca.d[8]  = D0(e0w1,  W_e01,             1024, 1024, 1024, 0,    1024);
  ca.d[9]  = D0(e1w1,  W_e01+1024*1024,   1024, 1024, 1024, 0,    1024);
  ca.d[10] = D0(e0w2,  W_e0w2,            1024, 1024, 1024, 0,    1024);
  ca.d[11] = D0(e1w2,  W_e1w2,            1024, 1024, 1024, 0,    1024);
  ca.d[12] = D0(dnw,   W_down,             256, 1024, 1024, 0,    1024);
  ca.d[13] = D0(upw,   W_up,              1024,  256,  256, 0,    256);
  ca.d[14] = D1(Wf_b,  bias768,       256);
  ca.d[15] = D1(Wu_b,  bias768+256,   256);
  ca.d[16] = D1(Win_b, bias768+512,   256);
  ca.d[17] = CvtDesc{Wo_b, pwb, nullptr, bias2, 1024, 1024, 0, 0, 0, 2};
  ca.d[18] = D1(e0b1,  bias01,       1024);
  ca.d[19] = D1(e1b1,  bias01+1024,  1024);
  cvt_all<<<20*64, 256, 0, stream>>>(ca);

  rmsnorm_k<<<NROWS, 256, 0, stream>>>(x, normw, A2);
  dwconv_k<<<(NROWS*DD)/256, 256, 0, stream>>>(A2, dwk, dwb, A2);

  // G2: fxu = xn @ [Wf_x;Wu_x;Win]^T + bias768   (f32)
  gemm_bt<0,0,0,0><<<64*6, 256, 0, stream>>>(A2, W_fxuwin, bias768, nullptr, nullptr,
                                             fxu, nullptr, nullptr, nullptr, nullptr, nullptr,
                                             NROWS, 768, 1024, 2048, 1024, 6, 1<<30);
  // fused: block0 = scan (m2all, newmem); blocks 1..512 = G34 (ybuf)
  scan_g34_k<<<513, 512, 0, stream>>>(fxu, W_fum, mem0, m2all,
                                      (float*)d_out + (size_t)NROWS*DD,
                                      A2, B2, bias2, x, ybuf);
  // G5: ybuf += m2 @ Wo_m^T ; ybf = bf16(ybuf)   (permuted rows t*4+b -> b*L+t)
  gemm_bt<0,3,1,0><<<64*8, 256, 0, stream>>>(m2all, W_om, nullptr, nullptr, nullptr,
                                             ybuf, ybf, nullptr, nullptr, nullptr, nullptr,
                                             NROWS, 1024, 256, 256, 256, 8, 1<<30);
  // experts stage 1 (fused): h01 = silu(ybf @ [e0w1;e1w1]^T + [e0b1;e1b1])
  gemm_bt<1,2,0,0><<<64*16, 256, 0, stream>>>(ybf, W_e01, bias01, nullptr, nullptr,
                                              h01, nullptr, nullptr, nullptr, nullptr, nullptr,
                                              NROWS, 2048, 1024, 1024, 1024, 16, 1<<30);
  // experts stage 2, both in ONE dispatch (DUAL pointer select)
  gemm_bt<0,2,0,1><<<64*16, 256, 0, stream>>>(h01, W_e0w2, e0b2, nullptr, nullptr,
                                              e0v, nullptr,
                                              h01+1024, W_e1w2, e1b2, e1v,
                                              NROWS, 1024, 1024, 2048, 1024, 8, 512);
  // router softmax + expert mix + final rmsnorm (in-place into ybuf / y2bf)
  combine_k<<<NROWS, 256, 0, stream>>>(ybuf, e0v, e1v, rw, rb, fnw, y2bf);
  // G10: hd = gelu(y2 @ down^T + down_b)   (bf16)
  gemm_bt<2,2,0,0><<<64*2, 256, 0, stream>>>(y2bf, W_down, dnb, nullptr, nullptr,
                                             hd, nullptr, nullptr, nullptr, nullptr, nullptr,
                                             NROWS, 256, 1024, 1024, 1024, 2, 1<<30);
  // G11: out = hd @ up^T + up_b + y2 + x
  gemm_bt<0,0,0,0><<<64*8, 256, 0, stream>>>(hd, W_up, upb, y2, x,
                                             (float*)d_out, nullptr, nullptr, nullptr, nullptr, nullptr,
                                             NROWS, 1024, 256, 256, 256, 8, 1<<30);
}

// Round 8
// 1873.471 us; speedup vs baseline: 1.3273x; 1.0393x over previous
//
#include <hip/hip_runtime.h>
#include <hip/hip_bf16.h>

#define DD 1024
#define MDD 256
#define LL 2048
#define BB 4
#define NROWS (BB*LL)   // 8192

typedef short bf16x8 __attribute__((ext_vector_type(8)));
typedef float f32x4 __attribute__((ext_vector_type(4)));
typedef int   i32x4 __attribute__((ext_vector_type(4)));

__device__ __forceinline__ short f2b(float x){
  __hip_bfloat16 h = __float2bfloat16(x);
  return *reinterpret_cast<short*>(&h);
}
__device__ __forceinline__ float b2f(short s){
  return __uint_as_float(((unsigned)(unsigned short)s) << 16);
}
__device__ __forceinline__ float frcp(float x){
#if __has_builtin(__builtin_amdgcn_rcpf)
  return __builtin_amdgcn_rcpf(x);
#else
  float r; asm("v_rcp_f32 %0, %1" : "=v"(r) : "v"(x)); return r;
#endif
}
__device__ __forceinline__ float fsigmoid(float x){
  return frcp(1.f + __expf(-x));
}
// select a[kg] without dynamic vector indexing (rule #20): 3 cndmask
__device__ __forceinline__ float sel4(f32x4 a, int kg){
  float lo = (kg & 1) ? a[1] : a[0];
  float hi = (kg & 1) ? a[3] : a[2];
  return (kg & 2) ? hi : lo;
}

// ---------------- fused weight conversion / bias prep (one launch) ----------------
struct CvtDesc {
  const float* src; const float* src2; short* dstb; float* dstf;
  int n, cols, sld, soff, dld, mode;
};
struct CvtArgs { CvtDesc d[20]; };

__global__ __launch_bounds__(256) void cvt_all(CvtArgs a){
  int di = blockIdx.x >> 6;
  CvtDesc d = a.d[di];
  int base = (blockIdx.x & 63)*256 + threadIdx.x;
  for (int i = base; i < d.n; i += 64*256){
    int r = i / d.cols, c = i - r*d.cols;
    float v = d.src[(size_t)r*d.sld + d.soff + c];
    if (d.mode == 2) v += d.src2[i];
    if (d.mode == 0) d.dstb[(size_t)r*d.dld + c] = f2b(v);
    else             d.dstf[i] = v;
  }
}

// ---------------- rmsnorm (f32 in -> bf16 out, strided out) ----------------
__global__ __launch_bounds__(256) void rmsnorm_k(const float* __restrict__ x,
                                                 const float* __restrict__ w,
                                                 short* __restrict__ xn){
  int row = blockIdx.x, tid = threadIdx.x;
  const float* xr = x + (size_t)row*DD;
  float4 v = *(const float4*)&xr[tid*4];
  float ss = v.x*v.x + v.y*v.y + v.z*v.z + v.w*v.w;
  __shared__ float red[256];
  red[tid] = ss; __syncthreads();
  for (int s = 128; s > 0; s >>= 1){ if (tid < s) red[tid] += red[tid+s]; __syncthreads(); }
  float scale = rsqrtf(red[0]/(float)DD + 1e-6f);
  const float* wr = w + tid*4;
  short4 o;
  o.x = f2b(v.x*wr[0]*scale); o.y = f2b(v.y*wr[1]*scale);
  o.z = f2b(v.z*wr[2]*scale); o.w = f2b(v.w*wr[3]*scale);
  *(short4*)&xn[(size_t)row*2048 + tid*4] = o;
}

// ---------------- depthwise causal conv K=5 (strided in/out: A2 layout) ----------------
__global__ __launch_bounds__(256) void dwconv_k(const short* __restrict__ xnA,
                                                const float* __restrict__ dwk,
                                                const float* __restrict__ dwb,
                                                short* __restrict__ xcA){
  size_t i = (size_t)blockIdx.x*256 + threadIdx.x;  // over NROWS*DD
  int d = (int)(i & (DD-1));
  int l = (int)((i >> 10) & (LL-1));
  int b = (int)(i >> 21);
  float acc = dwb[d];
  const float* kk = dwk + d*5;
  #pragma unroll
  for (int k = 0; k < 5; ++k){
    int ll = l + k - 4;
    if (ll >= 0) acc += b2f(xnA[((size_t)(b*LL + ll))*2048 + d]) * kk[k];
  }
  xcA[((size_t)(b*LL + l))*2048 + 1024 + d] = f2b(acc);
}

// ---------------- generic bf16 MFMA GEMM: C = act(A @ Bw^T + bias) (+adds) ----------------
// OUTMODE: 0=f32 store, 1=f32 accumulate, 2=bf16 store, 3=f32 accumulate + bf16 2nd out.
// ACT: 0 none, 1 silu, 2 exact gelu. DUAL: blocks >= nsplit use the _b pointer set.
// All grids are multiples of 8 -> bijective XCD swizzle groups bm-panels per XCD L2.
template<int ACT, int OUTMODE, int PERMUTE, int DUAL>
__global__ __launch_bounds__(256) void gemm_bt(
    const short* __restrict__ A, const short* __restrict__ Bw,
    const float* __restrict__ bias, const float* __restrict__ add0,
    const float* __restrict__ add1, void* __restrict__ Cout, short* __restrict__ Cout2,
    const short* A_b, const short* Bw_b, const float* bias_b, void* Cout_b,
    int M, int N, int K, int lda, int ldb, int nbn, int nsplit){
  __shared__ __align__(16) short As[128*32];
  __shared__ __align__(16) short Bs[128*32];
  int bid = (int)blockIdx.x;
  bid = (bid & 7)*((int)gridDim.x >> 3) + (bid >> 3);   // XCD swizzle (grid%8==0)
  if (DUAL && bid >= nsplit){
    A = A_b; Bw = Bw_b; bias = bias_b; Cout = Cout_b; bid -= nsplit;
  }
  int bm = bid / nbn, bn = bid % nbn;
  int tid = threadIdx.x, lane = tid & 63, w = tid >> 6;
  int wm = (w >> 1)*64, wn = (w & 1)*64;
  const int r0 = lane & 15, kg = lane >> 4;

  f32x4 acc[4][4];
  #pragma unroll
  for (int i = 0; i < 4; ++i)
    #pragma unroll
    for (int j = 0; j < 4; ++j)
      #pragma unroll
      for (int r = 0; r < 4; ++r) acc[i][j][r] = 0.f;

  const int c0 = w*64 + lane;
  const int c1 = c0 + 256;
  const short* a0 = &A [(size_t)(bm*128 + (c0 >> 2))*lda + (c0 & 3)*8];
  const short* a1 = &A [(size_t)(bm*128 + (c1 >> 2))*lda + (c1 & 3)*8];
  const short* b0 = &Bw[(size_t)(bn*128 + (c0 >> 2))*ldb + (c0 & 3)*8];
  const short* b1 = &Bw[(size_t)(bn*128 + (c1 >> 2))*ldb + (c1 & 3)*8];

  for (int k0 = 0; k0 < K; k0 += 32){
    __builtin_amdgcn_global_load_lds((const __attribute__((address_space(1))) void*)(a0 + k0),
                                     (__attribute__((address_space(3))) void*)&As[w*512], 16, 0, 0);
    __builtin_amdgcn_global_load_lds((const __attribute__((address_space(1))) void*)(b0 + k0),
                                     (__attribute__((address_space(3))) void*)&Bs[w*512], 16, 0, 0);
    __builtin_amdgcn_global_load_lds((const __attribute__((address_space(1))) void*)(a1 + k0),
                                     (__attribute__((address_space(3))) void*)&As[2048 + w*512], 16, 0, 0);
    __builtin_amdgcn_global_load_lds((const __attribute__((address_space(1))) void*)(b1 + k0),
                                     (__attribute__((address_space(3))) void*)&Bs[2048 + w*512], 16, 0, 0);
    __syncthreads();
    bf16x8 av[4], bv[4];
    #pragma unroll
    for (int i = 0; i < 4; ++i) av[i] = *(const bf16x8*)&As[(wm + i*16 + r0)*32 + kg*8];
    #pragma unroll
    for (int j = 0; j < 4; ++j) bv[j] = *(const bf16x8*)&Bs[(wn + j*16 + r0)*32 + kg*8];
    #pragma unroll
    for (int i = 0; i < 4; ++i)
      #pragma unroll
      for (int j = 0; j < 4; ++j)
        acc[i][j] = __builtin_amdgcn_mfma_f32_16x16x32_bf16(av[i], bv[j], acc[i][j], 0, 0, 0);
    __syncthreads();
  }

  #pragma unroll
  for (int i = 0; i < 4; ++i){
    int grb = bm*128 + wm + i*16 + kg*4;
    #pragma unroll
    for (int j = 0; j < 4; ++j){
      int gc = bn*128 + wn + j*16 + r0;
      float bvv = bias ? bias[gc] : 0.f;
      #pragma unroll
      for (int r = 0; r < 4; ++r){
        int gr = grb + r;
        float v = acc[i][j][r] + bvv;
        if (ACT == 1) v = v / (1.f + __expf(-v));
        else if (ACT == 2) v = 0.5f*v*(1.f + erff(v*0.70710678118f));
        size_t orow = PERMUTE ? (size_t)((gr & 3)*LL + (gr >> 2)) : (size_t)gr;
        size_t oi = orow*(size_t)N + gc;
        if (add0) v += add0[oi];
        if (add1) v += add1[oi];
        if (OUTMODE == 0) ((float*)Cout)[oi] = v;
        else if (OUTMODE == 1) ((float*)Cout)[oi] += v;
        else if (OUTMODE == 2) ((short*)Cout)[oi] = f2b(v);
        else {
          float nv = ((float*)Cout)[oi] + v;
          ((float*)Cout)[oi] = nv;
          Cout2[oi] = f2b(nv);
        }
      }
    }
  }
}

// ---------------- fused: block 0 = sequential scan; blocks 1.. = G34 GEMM ----------------
__global__ __launch_bounds__(512, 2) void scan_g34_k(
    const float* __restrict__ fxu, const short* __restrict__ Wfu,
    const float* __restrict__ m0, short* __restrict__ m2all, float* __restrict__ newmem,
    const short* __restrict__ A2, const short* __restrict__ B2,
    const float* __restrict__ bias2, const float* __restrict__ xres,
    float* __restrict__ ybuf){
  __shared__ __align__(16) short lds[8192];   // 16KB; scan uses first 2176 shorts
  const int tid = threadIdx.x, lane = tid & 63, w = tid >> 6;
  const int r0 = lane & 15, kg = lane >> 4;

  if (blockIdx.x != 0){
    // ---------- G34 GEMM branch: 128x128 tile, 8 waves (wave = 64x32 subtile) ----------
    int g = (int)blockIdx.x - 1;        // 0..511
    g = (g & 7)*64 + (g >> 3);          // XCD swizzle
    int bm = g >> 3, bn = g & 7;
    short* As = lds;          // [128][32]
    short* Bs = lds + 4096;
    int wm = (w >> 2)*64, wn = (w & 3)*32;
    f32x4 acc[4][2];
    #pragma unroll
    for (int i = 0; i < 4; ++i)
      #pragma unroll
      for (int j = 0; j < 2; ++j)
        #pragma unroll
        for (int r = 0; r < 4; ++r) acc[i][j][r] = 0.f;

    const int c = tid;  // chunk 0..511: row=c>>2, seg=c&3
    const short* ag = &A2[(size_t)(bm*128 + (c >> 2))*2048 + (c & 3)*8];
    const short* bg = &B2[(size_t)(bn*128 + (c >> 2))*2048 + (c & 3)*8];

    for (int k0 = 0; k0 < 2048; k0 += 32){
      __builtin_amdgcn_global_load_lds((const __attribute__((address_space(1))) void*)(ag + k0),
                                       (__attribute__((address_space(3))) void*)&As[w*512], 16, 0, 0);
      __builtin_amdgcn_global_load_lds((const __attribute__((address_space(1))) void*)(bg + k0),
                                       (__attribute__((address_space(3))) void*)&Bs[w*512], 16, 0, 0);
      __syncthreads();
      bf16x8 av[4], bv[2];
      #pragma unroll
      for (int i = 0; i < 4; ++i) av[i] = *(const bf16x8*)&As[(wm + i*16 + r0)*32 + kg*8];
      #pragma unroll
      for (int j = 0; j < 2; ++j) bv[j] = *(const bf16x8*)&Bs[(wn + j*16 + r0)*32 + kg*8];
      #pragma unroll
      for (int i = 0; i < 4; ++i)
        #pragma unroll
        for (int j = 0; j < 2; ++j)
          acc[i][j] = __builtin_amdgcn_mfma_f32_16x16x32_bf16(av[i], bv[j], acc[i][j], 0, 0, 0);
      __syncthreads();
    }
    #pragma unroll
    for (int i = 0; i < 4; ++i){
      int grb = bm*128 + wm + i*16 + kg*4;
      #pragma unroll
      for (int j = 0; j < 2; ++j){
        int gc = bn*128 + wn + j*16 + r0;
        float bvv = bias2[gc];
        #pragma unroll
        for (int r = 0; r < 4; ++r){
          size_t oi = (size_t)(grb + r)*1024 + gc;
          ybuf[oi] = acc[i][j][r] + bvv + xres[oi];
        }
      }
    }
    return;
  }

  // ---------- scan branch (block 0) ----------
  short* mA0 = lds;            // [4][272] x2 buffers
  short* mA1 = lds + 1088;
  const int j0 = w*32 + r0;

  // gate weights laundered BY VALUE through opaque asm (no remat of the loads).
  bf16x8 bw[2][2][8];
  #pragma unroll
  for (int fu = 0; fu < 2; ++fu)
    #pragma unroll
    for (int p = 0; p < 2; ++p)
      #pragma unroll
      for (int kt = 0; kt < 8; ++kt){
        i32x4 ld = *(const i32x4*)&Wfu[(size_t)(fu*256 + w*32 + p*16 + r0)*256 + kt*32 + kg*8];
        asm volatile("" : "+v"(ld));
        bw[fu][p][kt] = __builtin_bit_cast(bf16x8, ld);
      }

  float m_reg0 = m0[kg*256 + j0];
  float m_reg1 = m0[kg*256 + j0 + 16];

  // incrementing pointers: pfu -> f/u row of step t+1; px -> x row of step t+2;
  // pm -> m2all row of step t. Constant strides, no per-step 64-bit mads.
  const float* pfu;
  const float* px;
  short* pm = m2all + (size_t)kg*256 + j0;
  float cf0, cf1, cu0, cu1, xmc0, xmc1, nx0, nx1;
  {
    const float* b0p = fxu + (size_t)kg*LL*768 + j0;
    cf0 = b0p[0];    cf1 = b0p[16];
    cu0 = b0p[256];  cu1 = b0p[272];
    float tx0 = b0p[512], tx1 = b0p[528];
    xmc0 = tx0*fsigmoid(tx0);  xmc1 = tx1*fsigmoid(tx1);
    nx0 = b0p[768 + 512];  nx1 = b0p[768 + 528];
    pfu = b0p + 768;
    px  = b0p + 2*768 + 512;
  }
  mA0[kg*272 + j0]      = f2b(m_reg0);
  mA0[kg*272 + j0 + 16] = f2b(m_reg1);
  __syncthreads();

  const short* mac = mA0;
  short*       man = mA1;

#define SCAN_STEP(DO_FU, DO_X)                                                         \
  {                                                                                    \
    bf16x8 af[8];                                                                      \
    _Pragma("unroll")                                                                  \
    for (int kt = 0; kt < 8; ++kt)                                                     \
      af[kt] = *(const bf16x8*)&mac[(r0 & 3)*272 + kt*32 + kg*8];                      \
    float xmn0 = nx0*fsigmoid(nx0);                                                    \
    float xmn1 = nx1*fsigmoid(nx1);                                                    \
    __builtin_amdgcn_s_setprio(1);                                                     \
    f32x4 aF0 = {0.f,0.f,0.f,0.f}, aF1 = {0.f,0.f,0.f,0.f};                            \
    f32x4 aU0 = {0.f,0.f,0.f,0.f}, aU1 = {0.f,0.f,0.f,0.f};                            \
    _Pragma("unroll")                                                                  \
    for (int kt = 0; kt < 8; ++kt){                                                    \
      aF0 = __builtin_amdgcn_mfma_f32_16x16x32_bf16(af[kt], bw[0][0][kt], aF0, 0, 0, 0); \
      aF1 = __builtin_amdgcn_mfma_f32_16x16x32_bf16(af[kt], bw[0][1][kt], aF1, 0, 0, 0); \
      aU0 = __builtin_amdgcn_mfma_f32_16x16x32_bf16(af[kt], bw[1][0][kt], aU0, 0, 0, 0); \
      aU1 = __builtin_amdgcn_mfma_f32_16x16x32_bf16(af[kt], bw[1][1][kt], aU1, 0, 0, 0); \
    }                                                                                  \
    __builtin_amdgcn_s_setprio(0);                                                     \
    float gF0 = sel4(aF0, kg), gF1 = sel4(aF1, kg);                                    \
    float gU0 = sel4(aU0, kg), gU1 = sel4(aU1, kg);                                    \
    float f0 = fsigmoid(gF0 + cf0);                                                    \
    float f1 = fsigmoid(gF1 + cf1);                                                    \
    float u0 = fsigmoid(gU0 + cu0);                                                    \
    float u1 = fsigmoid(gU1 + cu1);                                                    \
    m_reg0 = f0*m_reg0 + u0*xmc0;                                                      \
    m_reg1 = f1*m_reg1 + u1*xmc1;                                                      \
    short mb0 = f2b(m_reg0), mb1 = f2b(m_reg1);                                        \
    pm[0] = mb0; pm[16] = mb1; pm += 1024;                                             \
    xmc0 = xmn0; xmc1 = xmn1;                                                          \
    if (DO_FU){                                                                        \
      cf0 = pfu[0];    cf1 = pfu[16];                                                  \
      cu0 = pfu[256];  cu1 = pfu[272];                                                 \
      pfu += 768;                                                                      \
    }                                                                                  \
    if (DO_X){                                                                         \
      nx0 = px[0]; nx1 = px[16]; px += 768;                                            \
    }                                                                                  \
    man[kg*272 + j0]      = mb0;                                                       \
    man[kg*272 + j0 + 16] = mb1;                                                       \
    asm volatile("s_waitcnt lgkmcnt(0)" ::: "memory");                                 \
    __builtin_amdgcn_sched_barrier(0);                                                 \
    __builtin_amdgcn_s_barrier();                                                      \
    __builtin_amdgcn_sched_barrier(0);                                                 \
    { const short* tmp_ = mac; mac = man; man = (short*)tmp_; }                        \
  }

  for (int t = 0; t < LL - 2; ++t) SCAN_STEP(1, 1)
  SCAN_STEP(1, 0)   // t = LL-2: f/u for last step already needed; no x beyond
  SCAN_STEP(0, 0)   // t = LL-1: no prefetch
#undef SCAN_STEP

  newmem[kg*256 + j0]      = m_reg0;
  newmem[kg*256 + j0 + 16] = m_reg1;
}

// ---------------- router + expert combine + final rmsnorm ----------------
__global__ __launch_bounds__(256) void combine_k(
    float* __restrict__ y, const short* __restrict__ e0, const short* __restrict__ e1,
    const float* __restrict__ rw, const float* __restrict__ rb,
    const float* __restrict__ fw, short* __restrict__ y2bf){
  int row = blockIdx.x, tid = threadIdx.x;
  size_t base = (size_t)row*DD + tid*4;
  float4 vy = *(const float4*)&y[base];
  short4 s0 = *(const short4*)&e0[base];
  short4 s1 = *(const short4*)&e1[base];
  float4 w0 = *(const float4*)&rw[tid*4];
  float4 w1 = *(const float4*)&rw[DD + tid*4];
  float d0 = vy.x*w0.x + vy.y*w0.y + vy.z*w0.z + vy.w*w0.w;
  float d1 = vy.x*w1.x + vy.y*w1.y + vy.z*w1.z + vy.w*w1.w;
  __shared__ float redA[256], redB[256];
  redA[tid] = d0; redB[tid] = d1; __syncthreads();
  for (int s = 128; s > 0; s >>= 1){
    if (tid < s){ redA[tid] += redA[tid+s]; redB[tid] += redB[tid+s]; }
    __syncthreads();
  }
  float l0 = redA[0] + rb[0], l1 = redB[0] + rb[1];
  float p0 = 1.f/(1.f + __expf(l1 - l0));
  float p1 = 1.f - p0;
  float c0 = vy.x + p0*b2f(s0.x) + p1*b2f(s1.x);
  float c1 = vy.y + p0*b2f(s0.y) + p1*b2f(s1.y);
  float c2 = vy.z + p0*b2f(s0.z) + p1*b2f(s1.z);
  float c3 = vy.w + p0*b2f(s0.w) + p1*b2f(s1.w);
  float ss = c0*c0 + c1*c1 + c2*c2 + c3*c3;
  __syncthreads();
  redA[tid] = ss; __syncthreads();
  for (int s = 128; s > 0; s >>= 1){
    if (tid < s) redA[tid] += redA[tid+s];
    __syncthreads();
  }
  float scale = rsqrtf(redA[0]/(float)DD + 1e-6f);
  const float* fwp = fw + tid*4;
  float o0 = c0*fwp[0]*scale, o1 = c1*fwp[1]*scale, o2 = c2*fwp[2]*scale, o3 = c3*fwp[3]*scale;
  float4 ov; ov.x = o0; ov.y = o1; ov.z = o2; ov.w = o3;
  *(float4*)&y[base] = ov;
  short4 ob; ob.x = f2b(o0); ob.y = f2b(o1); ob.z = f2b(o2); ob.w = f2b(o3);
  *(short4*)&y2bf[base] = ob;
}

// ---------------- host ----------------
extern "C" void kernel_launch(void* const* d_in, const int* in_sizes, int n_in,
                              void* d_out, int out_size, void* d_ws, size_t ws_size,
                              hipStream_t stream){
  (void)in_sizes; (void)n_in; (void)out_size; (void)ws_size;
  const float* x     = (const float*)d_in[0];
  const float* mem0  = (const float*)d_in[1];
  const float* normw = (const float*)d_in[2];
  const float* dwk   = (const float*)d_in[3];
  const float* dwb   = (const float*)d_in[4];
  const float* pw    = (const float*)d_in[5];
  const float* pwb   = (const float*)d_in[6];
  const float* Win_w = (const float*)d_in[7];
  const float* Win_b = (const float*)d_in[8];
  const float* Wf_w  = (const float*)d_in[9];
  const float* Wf_b  = (const float*)d_in[10];
  const float* Wu_w  = (const float*)d_in[11];
  const float* Wu_b  = (const float*)d_in[12];
  const float* Wo_w  = (const float*)d_in[13];
  const float* Wo_b  = (const float*)d_in[14];
  const float* rw    = (const float*)d_in[15];
  const float* rb    = (const float*)d_in[16];
  const float* e0w1  = (const float*)d_in[17];
  const float* e0b1  = (const float*)d_in[18];
  const float* e0w2  = (const float*)d_in[19];
  const float* e0b2  = (const float*)d_in[20];
  const float* e1w1  = (const float*)d_in[21];
  const float* e1b1  = (const float*)d_in[22];
  const float* e1w2  = (const float*)d_in[23];
  const float* e1b2  = (const float*)d_in[24];
  const float* fnw   = (const float*)d_in[25];
  const float* dnw   = (const float*)d_in[26];
  const float* dnb   = (const float*)d_in[27];
  const float* upw   = (const float*)d_in[28];
  const float* upb   = (const float*)d_in[29];

  char* ws = (char*)d_ws;
  size_t off = 0;
  auto alloc = [&](size_t bytes)->char*{
    char* p = ws + off; off += (bytes + 255) & ~(size_t)255; return p;
  };
  short* A2       = (short*)alloc((size_t)NROWS*2048*2);   // [xn | xc] bf16
  short* B2       = (short*)alloc((size_t)1024*2048*2);    // [Wo_x | pw] bf16
  short* W_fxuwin = (short*)alloc((size_t)768*1024*2);
  short* W_fum    = (short*)alloc((size_t)512*256*2);
  short* W_om     = (short*)alloc((size_t)1024*256*2);
  short* W_e01    = (short*)alloc((size_t)2048*1024*2);    // [e0w1 ; e1w1]
  short* W_e0w2   = (short*)alloc((size_t)1024*1024*2);
  short* W_e1w2   = (short*)alloc((size_t)1024*1024*2);
  short* W_down   = (short*)alloc((size_t)256*1024*2);
  short* W_up     = (short*)alloc((size_t)1024*256*2);
  float* bias768  = (float*)alloc(768*4);
  float* bias2    = (float*)alloc(1024*4);
  float* bias01   = (float*)alloc(2048*4);
  float* fxu      = (float*)alloc((size_t)NROWS*768*4);
  float* ybuf     = (float*)alloc((size_t)NROWS*DD*4);
  short* m2all    = (short*)alloc((size_t)NROWS*MDD*2);
  short* ybf      = (short*)alloc((size_t)NROWS*DD*2);
  short* e0v      = (short*)alloc((size_t)NROWS*DD*2);
  short* e1v      = (short*)alloc((size_t)NROWS*DD*2);
  short* h01      = (short*)alloc((size_t)NROWS*2048*2);   // [h0 | h1]
  short* hd = m2all;   // m2all dead after G5
  short* y2bf = ybf;   // ybf dead after expert first GEMM
  float* y2   = ybuf;  // in-place rmsnorm

  // ---- one fused weight-conversion launch (20 descriptors x 64 blocks) ----
  CvtArgs ca;
  auto D0 = [&](const float* s, short* db, int rows, int cols, int sld, int soff, int dld){
    return CvtDesc{s, nullptr, db, nullptr, rows*cols, cols, sld, soff, dld, 0};
  };
  auto D1 = [&](const float* s, float* df, int n){
    return CvtDesc{s, nullptr, nullptr, df, n, n, 0, 0, 0, 1};
  };
  ca.d[0]  = D0(Wo_w,  B2,                1024, 1024, 1280, 0,    2048);
  ca.d[1]  = D0(pw,    B2+1024,           1024, 1024, 1024, 0,    2048);
  ca.d[2]  = D0(Wf_w,  W_fxuwin,           256, 1024, 1280, 0,    1024);
  ca.d[3]  = D0(Wu_w,  W_fxuwin+256*1024,  256, 1024, 1280, 0,    1024);
  ca.d[4]  = D0(Win_w, W_fxuwin+512*1024,  256, 1024, 1024, 0,    1024);
  ca.d[5]  = D0(Wf_w,  W_fum,              256,  256, 1280, 1024, 256);
  ca.d[6]  = D0(Wu_w,  W_fum+256*256,      256,  256, 1280, 1024, 256);
  ca.d[7]  = D0(Wo_w,  W_om,              1024,  256, 1280, 1024, 256);
  ca.d[8]  = D0(e0w1,  W_e01,             1024, 1024, 1024, 0,    1024);
  ca.d[9]  = D0(e1w1,  W_e01+1024*1024,   1024, 1024, 1024, 0,    1024);
  ca.d[10] = D0(e0w2,  W_e0w2,            1024, 1024, 1024, 0,    1024);
  ca.d[11] = D0(e1w2,  W_e1w2,            1024, 1024, 1024, 0,    1024);
  ca.d[12] = D0(dnw,   W_down,             256, 1024, 1024, 0,    1024);
  ca.d[13] = D0(upw,   W_up,              1024,  256,  256, 0,    256);
  ca.d[14] = D1(Wf_b,  bias768,       256);
  ca.d[15] = D1(Wu_b,  bias768+256,   256);
  ca.d[16] = D1(Win_b, bias768+512,   256);
  ca.d[17] = CvtDesc{Wo_b, pwb, nullptr, bias2, 1024, 1024, 0, 0, 0, 2};
  ca.d[18] = D1(e0b1,  bias01,       1024);
  ca.d[19] = D1(e1b1,  bias01+1024,  1024);
  cvt_all<<<20*64, 256, 0, stream>>>(ca);

  rmsnorm_k<<<NROWS, 256, 0, stream>>>(x, normw, A2);
  dwconv_k<<<(NROWS*DD)/256, 256, 0, stream>>>(A2, dwk, dwb, A2);

  // G2: fxu = xn @ [Wf_x;Wu_x;Win]^T + bias768   (f32)
  gemm_bt<0,0,0,0><<<64*6, 256, 0, stream>>>(A2, W_fxuwin, bias768, nullptr, nullptr,
                                             fxu, nullptr, nullptr, nullptr, nullptr, nullptr,
                                             NROWS, 768, 1024, 2048, 1024, 6, 1<<30);
  // fused: block0 = scan (m2all, newmem); blocks 1..512 = G34 (ybuf)
  scan_g34_k<<<513, 512, 0, stream>>>(fxu, W_fum, mem0, m2all,
                                      (float*)d_out + (size_t)NROWS*DD,
                                      A2, B2, bias2, x, ybuf);
  // G5: ybuf += m2 @ Wo_m^T ; ybf = bf16(ybuf)   (permuted rows t*4+b -> b*L+t)
  gemm_bt<0,3,1,0><<<64*8, 256, 0, stream>>>(m2all, W_om, nullptr, nullptr, nullptr,
                                             ybuf, ybf, nullptr, nullptr, nullptr, nullptr,
                                             NROWS, 1024, 256, 256, 256, 8, 1<<30);
  // experts stage 1 (fused): h01 = silu(ybf @ [e0w1;e1w1]^T + [e0b1;e1b1])
  gemm_bt<1,2,0,0><<<64*16, 256, 0, stream>>>(ybf, W_e01, bias01, nullptr, nullptr,
                                              h01, nullptr, nullptr, nullptr, nullptr, nullptr,
                                              NROWS, 2048, 1024, 1024, 1024, 16, 1<<30);
  // experts stage 2, both in ONE dispatch (DUAL pointer select)
  gemm_bt<0,2,0,1><<<64*16, 256, 0, stream>>>(h01, W_e0w2, e0b2, nullptr, nullptr,
                                              e0v, nullptr,
                                              h01+1024, W_e1w2, e1b2, e1v,
                                              NROWS, 1024, 1024, 2048, 1024, 8, 512);
  // router softmax + expert mix + final rmsnorm (in-place into ybuf / y2bf)
  combine_k<<<NROWS, 256, 0, stream>>>(ybuf, e0v, e1v, rw, rb, fnw, y2bf);
  // G10: hd = gelu(y2 @ down^T + down_b)   (bf16)
  gemm_bt<2,2,0,0><<<64*2, 256, 0, stream>>>(y2bf, W_down, dnb, nullptr, nullptr,
                                             hd, nullptr, nullptr, nullptr, nullptr, nullptr,
                                             NROWS, 256, 1024, 1024, 1024, 2, 1<<30);
  // G11: out = hd @ up^T + up_b + y2 + x
  gemm_bt<0,0,0,0><<<64*8, 256, 0, stream>>>(hd, W_up, upb, y2, x,
                                             (float*)d_out, nullptr, nullptr, nullptr, nullptr, nullptr,
                                             NROWS, 1024, 256, 256, 256, 8, 1<<30);
}